// Round 7
// baseline (549.449 us; speedup 1.0000x reference)
//
#include <hip/hip_runtime.h>
#include <math.h>

typedef long long ll;
typedef unsigned int uint;
typedef unsigned short ushort;
typedef __attribute__((ext_vector_type(4))) float f32x4;
typedef __attribute__((ext_vector_type(8))) short bf16x8;

#define SZ 102400LL
#define RS 40960LL

// split fp32 -> hi/lo bf16 (RNE both)
__device__ inline void split2(float v, ushort& h, ushort& l)
{
    uint u = __float_as_uint(v);
    uint uh = u + (0x7FFFu + ((u >> 16) & 1u));
    h = (ushort)(uh >> 16);
    float hf = __uint_as_float((uint)h << 16);
    float d = v - hf;
    uint ud = __float_as_uint(d);
    l = (ushort)((ud + (0x7FFFu + ((ud >> 16) & 1u))) >> 16);
}
__device__ inline float us2f(ushort h, ushort l)
{
    return __uint_as_float((uint)h << 16) + __uint_as_float((uint)l << 16);
}

// ---------------------------------------------------------------------------
// setup: transpose-splits of Wq/Wk/Wv (per layer), plain split P, emb splits
// (plain + transposed), q0 build. 407 blocks.
// ---------------------------------------------------------------------------
__global__ __launch_bounds__(256) void sp_k(
    const float* __restrict__ Wq, const float* __restrict__ Wk,
    const float* __restrict__ Wv, const float* __restrict__ P,
    const float* __restrict__ emb,
    ushort* __restrict__ WqTs, ushort* __restrict__ WkTs, ushort* __restrict__ WvTs,
    ushort* __restrict__ Ps, ushort* __restrict__ embs, ushort* __restrict__ embTs,
    float* __restrict__ q0)
{
    int bid = blockIdx.x, tid = threadIdx.x;
    if (bid < 225) {                       // transpose-split 320x320 mats
        int m = bid / 25, t = bid % 25;
        const float* mats[3] = {Wq, Wk, Wv};
        ushort* dsts[3] = {WqTs, WkTs, WvTs};
        const float* src = mats[m / 3] + (ll)(m % 3) * SZ;
        ushort* dst = dsts[m / 3] + (ll)(m % 3) * SZ;
        int r0 = (t / 5) * 64, c0 = (t % 5) * 64;
        __shared__ float T[64][65];
        #pragma unroll
        for (int s = 0; s < 4; ++s) {      // load 64x64 tile: 1024 float4
            int idx = s * 256 + tid;
            int r = idx >> 4, cq = (idx & 15) * 4;
            *(float4*)&T[r][cq] = *(const float4*)(src + (ll)(r0 + r) * 320 + c0 + cq);
        }
        __syncthreads();
        {                                  // store: 256 items (c, kq) x 16 k each
            int c = tid >> 2, kq = (tid & 3) * 16;
            bf16x8 h0, h1, l0, l1;
            #pragma unroll
            for (int u = 0; u < 8; ++u) {
                ushort h, l;
                split2(T[kq + u][c], h, l);     h0[u] = (short)h; l0[u] = (short)l;
                split2(T[kq + 8 + u][c], h, l); h1[u] = (short)h; l1[u] = (short)l;
            }
            ushort* dh = dst + (ll)(c0 + c) * 320 + r0 + kq;
            *(bf16x8*)dh = h0; *(bf16x8*)(dh + 8) = h1;
            *(bf16x8*)(dh + 3 * SZ) = l0; *(bf16x8*)(dh + 3 * SZ + 8) = l1;
        }
    } else if (bid < 375) {                // plain split P (3*SZ)
        ll off = (ll)(bid - 225) * 2048 + tid * 8;
        float4 v0 = *(const float4*)(P + off);
        float4 v1 = *(const float4*)(P + off + 4);
        float vals[8] = {v0.x,v0.y,v0.z,v0.w,v1.x,v1.y,v1.z,v1.w};
        bf16x8 hv, lv;
        #pragma unroll
        for (int u = 0; u < 8; ++u) { ushort h,l; split2(vals[u],h,l);
                                      hv[u]=(short)h; lv[u]=(short)l; }
        *(bf16x8*)(Ps + off) = hv;
        *(bf16x8*)(Ps + off + 3 * SZ) = lv;
    } else if (bid < 383) {                // plain split emb (16384)
        ll off = (ll)(bid - 375) * 2048 + tid * 8;
        float4 v0 = *(const float4*)(emb + off);
        float4 v1 = *(const float4*)(emb + off + 4);
        float vals[8] = {v0.x,v0.y,v0.z,v0.w,v1.x,v1.y,v1.z,v1.w};
        bf16x8 hv, lv;
        #pragma unroll
        for (int u = 0; u < 8; ++u) { ushort h,l; split2(vals[u],h,l);
                                      hv[u]=(short)h; lv[u]=(short)l; }
        *(bf16x8*)(embs + off) = hv;
        *(bf16x8*)(embs + off + 16384) = lv;
    } else if (bid < 387) {                // transpose-split emb -> embTs
        int t = bid - 383;
        int r0 = (t >> 1) * 64, c0 = (t & 1) * 64;
        __shared__ float T[64][65];
        {
            int r = tid >> 2, cq = (tid & 3) * 4;
            *(float4*)&T[r][cq]      = *(const float4*)(emb + (ll)(r0 + r) * 128 + c0 + cq);
            *(float4*)&T[r][cq + 16] = *(const float4*)(emb + (ll)(r0 + r) * 128 + c0 + cq + 16);
            *(float4*)&T[r][cq + 32] = *(const float4*)(emb + (ll)(r0 + r) * 128 + c0 + cq + 32);
            *(float4*)&T[r][cq + 48] = *(const float4*)(emb + (ll)(r0 + r) * 128 + c0 + cq + 48);
        }
        __syncthreads();
        {
            int c = tid >> 2, kq = (tid & 3) * 16;
            bf16x8 h0, h1, l0, l1;
            #pragma unroll
            for (int u = 0; u < 8; ++u) {
                ushort h, l;
                split2(T[kq + u][c], h, l);     h0[u]=(short)h; l0[u]=(short)l;
                split2(T[kq + 8 + u][c], h, l); h1[u]=(short)h; l1[u]=(short)l;
            }
            ushort* dh = embTs + (ll)(c0 + c) * 128 + r0 + kq;
            *(bf16x8*)dh = h0; *(bf16x8*)(dh + 8) = h1;
            *(bf16x8*)(dh + 16384) = l0; *(bf16x8*)(dh + 16384 + 8) = l1;
        }
    } else {                               // q0[c][i]
        ll base = (ll)(bid - 387) * 2048;
        #pragma unroll
        for (int s = 0; s < 8; ++s) {
            ll id = base + s * 256 + tid;
            int c = (int)(id / 320), i = (int)(id % 320);
            q0[id] = (i >= 192) ? emb[(ll)(i - 192) * 128 + c] : 0.f;
        }
    }
}

// ---------------------------------------------------------------------------
// Gram via MFMA (round-5-verified): part[p][b][t], 960 blocks.
// ---------------------------------------------------------------------------
__global__ __launch_bounds__(256) void gram_mfma_k(const float* __restrict__ x,
                                                   float* __restrict__ part)
{
    int flat = blockIdx.x;
    int swz = (flat & 7) * 120 + (flat >> 3);
    int b = swz / 60;
    int rr = swz - b * 60;
    int p = rr / 15, t = rr - p * 15;
    int ti = 0, rem = t;
    while (rem >= 5 - ti) { rem -= 5 - ti; ++ti; }
    int tj = ti + rem;
    int i0 = ti * 64, j0 = tj * 64;
    bool diag = (ti == tj);
    const float* X = x + (ll)b * 320 * 2048;
    __shared__ __align__(16) ushort Ah[64 * 40], Al_[64 * 40], Bh[64 * 40], Bl_[64 * 40];
    int tid = threadIdx.x;
    int wv = tid >> 6, lane = tid & 63;
    int lr = lane & 15, kb = (lane >> 4) * 8;
    int cr = tid >> 2, ck = (tid & 3) * 8;
    f32x4 hh[4], hl[4], lh[4];
    f32x4 zz = {0.f, 0.f, 0.f, 0.f};
    #pragma unroll
    for (int f = 0; f < 4; ++f) { hh[f] = zz; hl[f] = zz; lh[f] = zz; }
    const ushort* BhS = diag ? Ah : Bh;
    const ushort* BlS = diag ? Al_ : Bl_;

    for (int it = 0; it < 16; ++it) {
        int kg0 = p * 512 + it * 32;
        {
            const float* src = X + (ll)(i0 + cr) * 2048 + kg0 + ck;
            float4 v0 = *(const float4*)src;
            float4 v1 = *(const float4*)(src + 4);
            float vals[8] = {v0.x,v0.y,v0.z,v0.w,v1.x,v1.y,v1.z,v1.w};
            if (kg0 + ck + 7 >= 2047) {
                #pragma unroll
                for (int u = 0; u < 8; ++u) if (kg0 + ck + u >= 2047) vals[u] = 0.f;
            }
            bf16x8 hv, lv;
            #pragma unroll
            for (int u = 0; u < 8; ++u) { ushort h, l; split2(vals[u], h, l);
                                          hv[u] = (short)h; lv[u] = (short)l; }
            *(bf16x8*)&Ah[cr * 40 + ck] = hv;
            *(bf16x8*)&Al_[cr * 40 + ck] = lv;
        }
        if (!diag) {
            const float* src = X + (ll)(j0 + cr) * 2048 + kg0 + ck;
            float4 v0 = *(const float4*)src;
            float4 v1 = *(const float4*)(src + 4);
            float vals[8] = {v0.x,v0.y,v0.z,v0.w,v1.x,v1.y,v1.z,v1.w};
            if (kg0 + ck + 7 >= 2047) {
                #pragma unroll
                for (int u = 0; u < 8; ++u) if (kg0 + ck + u >= 2047) vals[u] = 0.f;
            }
            bf16x8 hv, lv;
            #pragma unroll
            for (int u = 0; u < 8; ++u) { ushort h, l; split2(vals[u], h, l);
                                          hv[u] = (short)h; lv[u] = (short)l; }
            *(bf16x8*)&Bh[cr * 40 + ck] = hv;
            *(bf16x8*)&Bl_[cr * 40 + ck] = lv;
        }
        __syncthreads();
        bf16x8 ah = *(const bf16x8*)&Ah[(wv * 16 + lr) * 40 + kb];
        bf16x8 al = *(const bf16x8*)&Al_[(wv * 16 + lr) * 40 + kb];
        #pragma unroll
        for (int f = 0; f < 4; ++f) {
            bf16x8 bh_ = *(const bf16x8*)&BhS[(f * 16 + lr) * 40 + kb];
            bf16x8 bl_ = *(const bf16x8*)&BlS[(f * 16 + lr) * 40 + kb];
            hh[f] = __builtin_amdgcn_mfma_f32_16x16x32_bf16(ah, bh_, hh[f], 0, 0, 0);
            hl[f] = __builtin_amdgcn_mfma_f32_16x16x32_bf16(ah, bl_, hl[f], 0, 0, 0);
            lh[f] = __builtin_amdgcn_mfma_f32_16x16x32_bf16(al, bh_, lh[f], 0, 0, 0);
        }
        __syncthreads();
    }
    float* out = part + (((ll)p * 16 + b) * 15 + t) * 4096;
    int orow0 = wv * 16 + (lane >> 4) * 4;
    #pragma unroll
    for (int f = 0; f < 4; ++f) {
        int col = f * 16 + lr;
        #pragma unroll
        for (int r = 0; r < 4; ++r)
            out[(orow0 + r) * 64 + col] = hh[f][r] + hl[f][r] + lh[f][r];
    }
}

// Sum 4 partials; write GxS splits (both triangles) + T1s splits for the
// identity-band rows (0:64, 192:320). Grid 240.
__global__ __launch_bounds__(256) void gram_red_k(const float* __restrict__ part,
                                                  ushort* __restrict__ GxS,
                                                  ushort* __restrict__ T1s)
{
    int bt = blockIdx.x;
    int b = bt / 15, t = bt % 15;
    int ti = 0, rem = t;
    while (rem >= 5 - ti) { rem -= 5 - ti; ++ti; }
    int tj = ti + rem;
    int i0 = ti * 64, j0 = tj * 64;
    int tid = threadIdx.x;
    int tx = tid & 15, rg = tid >> 4;
    bool wi = (ti == 0 || ti >= 3);
    bool wj = (tj == 0 || tj >= 3);
    ushort* Gb = GxS + (ll)b * SZ;
    ushort* Tsb = T1s + (ll)b * SZ;
    #pragma unroll
    for (int m = 0; m < 4; ++m) {
        int r = rg * 4 + m;
        float s[4] = {};
        for (int p = 0; p < 4; ++p) {
            const float* src = part + (((ll)p * 16 + b) * 15 + t) * 4096 + r * 64 + tx * 4;
            float4 v = *(const float4*)src;
            s[0]+=v.x; s[1]+=v.y; s[2]+=v.z; s[3]+=v.w;
        }
        #pragma unroll
        for (int u = 0; u < 4; ++u) {
            ushort h, l; split2(s[u], h, l);
            ll rd = (ll)(i0 + r) * 320 + j0 + tx * 4 + u;
            ll rt = (ll)(j0 + tx * 4 + u) * 320 + (i0 + r);
            Gb[rd] = h; Gb[rd + 16 * SZ] = l;
            Gb[rt] = h; Gb[rt + 16 * SZ] = l;
            if (wi) { Tsb[rd] = h; Tsb[rd + 16 * SZ] = l; }
            if (wj) { Tsb[rt] = h; Tsb[rt + 16 * SZ] = l; }
        }
    }
}

// ---------------------------------------------------------------------------
// Packed MFMA bf16x3 job kernel: C[bz](MxN) = alpha * A . BL^T + adds.
// A[i][k] k-contig (hi Ah, lo +aLo), BL[j][k] k-contig. K==0 -> copy epilogue.
// flags: 1 +Ci fp32 | 32 +Ci split-pair | 2 +Ci2 | 4 +Ci2^T (64: Ci2 is
// split-pair for both 2 and 4) | 8 write C fp32 | 16 write Cs splits.
// Split-pair strides/offsets are in USHORT units.
// ---------------------------------------------------------------------------
struct CJob {
    const ushort *Ah, *Bh;
    const void *Ci, *Ci2;
    float* C; ushort* Cs;
    ll aB, bB, ciB, ci2B, cB, csB;
    ll aLo, bLo, csLo, ciLo, ci2Lo;
    int aS, bS, ciS, ci2S, cS, csS;
    int K, tN, tpb, flags;
    float alpha;
};
struct CPack { CJob j[4]; };

__global__ __launch_bounds__(256) void mchain_k(CPack jp, int c0, int c1, int c2)
{
    int bid = blockIdx.x;
    int ji, local;
    if (bid < c0)      { ji = 0; local = bid; }
    else if (bid < c1) { ji = 1; local = bid - c0; }
    else if (bid < c2) { ji = 2; local = bid - c1; }
    else               { ji = 3; local = bid - c2; }
    CJob j = jp.j[ji];
    int bz = local / j.tpb;
    int t = local - bz * j.tpb;
    int i0 = (t / j.tN) * 64, j0 = (t % j.tN) * 64;
    int tid = threadIdx.x;
    int wv = tid >> 6, lane = tid & 63;
    int lr = lane & 15, kb = (lane >> 4) * 8;
    f32x4 hh[4], cx[4];
    f32x4 zz = {0.f,0.f,0.f,0.f};
    #pragma unroll
    for (int f = 0; f < 4; ++f) { hh[f] = zz; cx[f] = zz; }

    if (j.K > 0) {
        const ushort* Ar = j.Ah + (ll)bz * j.aB + (ll)(i0 + wv * 16 + lr) * j.aS + kb;
        const ushort* Br = j.Bh + (ll)bz * j.bB + (ll)(j0 + lr) * j.bS + kb;
        for (int k0 = 0; k0 < j.K; k0 += 32) {
            bf16x8 ah = *(const bf16x8*)(Ar + k0);
            bf16x8 al = *(const bf16x8*)(Ar + j.aLo + k0);
            #pragma unroll
            for (int f = 0; f < 4; ++f) {
                const ushort* Bp = Br + (ll)f * 16 * j.bS + k0;
                bf16x8 bh = *(const bf16x8*)Bp;
                bf16x8 bl = *(const bf16x8*)(Bp + j.bLo);
                hh[f] = __builtin_amdgcn_mfma_f32_16x16x32_bf16(ah, bh, hh[f], 0, 0, 0);
                cx[f] = __builtin_amdgcn_mfma_f32_16x16x32_bf16(ah, bl, cx[f], 0, 0, 0);
                cx[f] = __builtin_amdgcn_mfma_f32_16x16x32_bf16(al, bh, cx[f], 0, 0, 0);
            }
        }
    }
    const float* Cif = (const float*)j.Ci;
    const ushort* Ciu = (const ushort*)j.Ci;
    const float* Ci2f = (const float*)j.Ci2;
    const ushort* Ci2u = (const ushort*)j.Ci2;
    float* Cp = j.C + (ll)bz * j.cB;
    ushort* Csp = j.Cs + (ll)bz * j.csB;
    int r0 = i0 + wv * 16 + ((lane >> 4) << 2);
    #pragma unroll
    for (int f = 0; f < 4; ++f) {
        int col = j0 + f * 16 + lr;
        #pragma unroll
        for (int r = 0; r < 4; ++r) {
            int row = r0 + r;
            float v = j.alpha * (hh[f][r] + cx[f][r]);
            if (j.flags & 1)
                v += Cif[(ll)bz * j.ciB + (ll)row * j.ciS + col];
            if (j.flags & 32) {
                const ushort* p = Ciu + (ll)bz * j.ciB + (ll)row * j.ciS + col;
                v += us2f(p[0], p[j.ciLo]);
            }
            if (j.flags & 64) {
                const ushort* b2 = Ci2u + (ll)bz * j.ci2B;
                if (j.flags & 2) { const ushort* p = b2 + (ll)row * j.ci2S + col;
                                   v += us2f(p[0], p[j.ci2Lo]); }
                if (j.flags & 4) { const ushort* p = b2 + (ll)col * j.ci2S + row;
                                   v += us2f(p[0], p[j.ci2Lo]); }
            } else {
                if (j.flags & 2) v += Ci2f[(ll)bz * j.ci2B + (ll)row * j.ci2S + col];
                if (j.flags & 4) v += Ci2f[(ll)bz * j.ci2B + (ll)col * j.ci2S + row];
            }
            if (j.flags & 8) Cp[(ll)row * j.cS + col] = v;
            if (j.flags & 16) {
                ushort h, l; split2(v, h, l);
                ushort* p = Csp + (ll)row * j.csS + col;
                p[0] = h; p[j.csLo] = l;
            }
        }
    }
}

// ---------------------------------------------------------------------------
// MFMA logits + softmax. Grid (32, 16), 256 thr. A = x^T tile (LDS transpose +
// split), B = LB splits (global, L2-hot). 24 MFMA / 32-K step.
// ---------------------------------------------------------------------------
__global__ __launch_bounds__(256) void logits_mfma_k(const float* __restrict__ x,
                                                     const ushort* __restrict__ LBs,
                                                     float* __restrict__ logits,
                                                     float* __restrict__ pred)
{
    int b = blockIdx.y;
    int i0 = blockIdx.x * 64;
    const float* X = x + (ll)b * 320 * 2048;
    const ushort* LB = LBs + (ll)b * RS;
    __shared__ float Xs_[2][32][68];
    int tid = threadIdx.x;
    int wv = tid >> 6, lane = tid & 63;
    int lr = lane & 15, kb = (lane >> 4) * 8;
    int lkk = tid >> 3, lq = tid & 7;
    f32x4 hh[8], cx[8];
    f32x4 zz = {0.f,0.f,0.f,0.f};
    #pragma unroll
    for (int f = 0; f < 8; ++f) { hh[f] = zz; cx[f] = zz; }
    float4 p0, p1;
    auto glb = [&](int k0) {
        const float* s = X + (ll)(k0 + lkk) * 2048 + i0 + lq * 8;
        p0 = *(const float4*)s; p1 = *(const float4*)(s + 4);
    };
    auto stl = [&](int buf) {
        *(float4*)&Xs_[buf][lkk][lq * 8] = p0;
        *(float4*)&Xs_[buf][lkk][lq * 8 + 4] = p1;
    };
    glb(0); stl(0);
    __syncthreads();
    for (int it = 0; it < 10; ++it) {
        int cur = it & 1;
        if (it < 9) glb((it + 1) * 32);
        bf16x8 ah, al;
        #pragma unroll
        for (int u = 0; u < 8; ++u) {
            ushort h, l;
            split2(Xs_[cur][kb + u][wv * 16 + lr], h, l);
            ah[u] = (short)h; al[u] = (short)l;
        }
        #pragma unroll
        for (int f = 0; f < 8; ++f) {
            const ushort* Bp = LB + (ll)(f * 16 + lr) * 320 + it * 32 + kb;
            bf16x8 bh = *(const bf16x8*)Bp;
            bf16x8 bl = *(const bf16x8*)(Bp + 16 * RS);
            hh[f] = __builtin_amdgcn_mfma_f32_16x16x32_bf16(ah, bh, hh[f], 0, 0, 0);
            cx[f] = __builtin_amdgcn_mfma_f32_16x16x32_bf16(ah, bl, cx[f], 0, 0, 0);
            cx[f] = __builtin_amdgcn_mfma_f32_16x16x32_bf16(al, bh, cx[f], 0, 0, 0);
        }
        if (it < 9) stl(cur ^ 1);
        __syncthreads();
    }
    #pragma unroll
    for (int r = 0; r < 4; ++r) {
        int n = i0 + wv * 16 + ((lane >> 4) << 2) + r;
        float v[8];
        float mx = -1e30f;
        #pragma unroll
        for (int f = 0; f < 8; ++f) { v[f] = hh[f][r] + cx[f][r]; mx = fmaxf(mx, v[f]); }
        #pragma unroll
        for (int off = 8; off; off >>= 1) mx = fmaxf(mx, __shfl_xor(mx, off));
        float e[8], sm = 0.f;
        #pragma unroll
        for (int f = 0; f < 8; ++f) { e[f] = expf(v[f] - mx); sm += e[f]; }
        #pragma unroll
        for (int off = 8; off; off >>= 1) sm += __shfl_xor(sm, off);
        float inv = 1.f / sm;
        ll ro = ((ll)b * 2048 + n) * 128 + lr;
        #pragma unroll
        for (int f = 0; f < 8; ++f) {
            logits[ro + f * 16] = v[f];
            pred[ro + f * 16] = e[f] * inv;
        }
    }
}

extern "C" void kernel_launch(void* const* d_in, const int* in_sizes, int n_in,
                              void* d_out, int out_size, void* d_ws, size_t ws_size,
                              hipStream_t stream)
{
    const float* x   = (const float*)d_in[0];
    const float* emb = (const float*)d_in[1];
    const float* Wq  = (const float*)d_in[2];
    const float* Wk  = (const float*)d_in[3];
    const float* Wv  = (const float*)d_in[4];
    const float* P   = (const float*)d_in[5];

    float* logits = (float*)d_out;
    float* pred   = logits + (ll)16 * 2048 * 128;

    float* w = (float*)d_ws;
    auto takef = [&](ll n) { float* p = w; w += n; return p; };
    ushort* GxS  = (ushort*)takef(16 * SZ); // alias: Xs (after LA)
    ushort* T1s  = (ushort*)takef(16 * SZ); // alias: Zts (after LG)
    ushort* Gs   = (ushort*)takef(16 * SZ);
    ushort* As   = (ushort*)takef(16 * SZ);
    ushort* Us   = (ushort*)takef(16 * SZ);
    float*  ATsF = takef(48 * SZ);          // part aliases front (3.93M < 4.92M)
    ushort* ATs  = (ushort*)ATsF;
    ushort* PVs  = (ushort*)takef(3 * SZ);
    ushort* KQTs = (ushort*)takef(3 * SZ);
    ushort* KQs  = (ushort*)takef(3 * SZ);
    ushort* Ps   = (ushort*)takef(3 * SZ);
    ushort* WqTs = (ushort*)takef(3 * SZ);
    ushort* WkTs = (ushort*)takef(3 * SZ);
    ushort* WvTs = (ushort*)takef(3 * SZ);
    ushort* embs = (ushort*)takef(16384);
    ushort* embTs= (ushort*)takef(16384);
    float*  q0f  = takef(RS);
    ushort* q1s  = (ushort*)takef(16 * RS); // alias: q3s
    ushort* q2s  = (ushort*)takef(16 * RS);
    ushort* LBs  = (ushort*)takef(16 * RS);
    ushort* Xs   = GxS;
    ushort* Zts  = T1s;
    float*  part = ATsF;
    ushort* q3s  = q1s;
    const float cinv = 1.f / 2047.f;

    auto JB = [](const ushort* Ah, ll aB, int aS, ll aLo,
                 const ushort* Bh, ll bB, int bS, ll bLo,
                 int K, int tM, int tN, float alpha, int flags,
                 const void* Ci, ll ciB, int ciS, ll ciLo,
                 const void* Ci2, ll ci2B, int ci2S, ll ci2Lo,
                 float* C, ll cB, int cS,
                 ushort* Cs, ll csB, int csS, ll csLo) {
        CJob j;
        j.Ah = Ah; j.Bh = Bh;
        j.Ci = Ci; j.Ci2 = Ci2; j.C = C; j.Cs = Cs;
        j.aB = aB; j.bB = bB; j.ciB = ciB; j.ci2B = ci2B; j.cB = cB; j.csB = csB;
        j.aLo = aLo; j.bLo = bLo; j.csLo = csLo; j.ciLo = ciLo; j.ci2Lo = ci2Lo;
        j.aS = aS; j.bS = bS; j.ciS = ciS; j.ci2S = ci2S; j.cS = cS; j.csS = csS;
        j.K = K; j.tN = tN; j.tpb = tM * tN; j.flags = flags; j.alpha = alpha;
        return j;
    };
    auto fire = [&](const CJob* js, const int* nb, int n) {
        CPack jp;
        int cum[4], tot = 0;
        for (int i = 0; i < 4; ++i) {
            jp.j[i] = js[i < n ? i : 0];
            tot += (i < n ? nb[i] : 0);
            cum[i] = tot;
        }
        mchain_k<<<tot, 256, 0, stream>>>(jp, cum[0], cum[1], cum[2]);
    };

    // 1) setup splits
    sp_k<<<407, 256, 0, stream>>>(Wq, Wk, Wv, P, emb,
                                  WqTs, WkTs, WvTs, Ps, embs, embTs, q0f);
    // 2-3) gram
    gram_mfma_k<<<960, 256, 0, stream>>>(x, part);
    gram_red_k<<<240, 256, 0, stream>>>(part, GxS, T1s);
    // 4) LA: T1mid = E*Gx[64:192] | PV = P*Wv | KQT = Wq^T Wk | KQ = Wk^T Wq
    {
        CJob js[4] = {
            JB(embs, 0, 128, 16384,  GxS + 64, SZ, 320, 16*SZ,  128, 2, 5, 1.f, 16,
               0,0,0,0, 0,0,0,0,  0,0,0,  T1s + 64*320, SZ, 320, 16*SZ),
            JB(Ps, SZ, 320, 3*SZ,  WvTs, SZ, 320, 3*SZ,  320, 5, 5, 1.f, 16,
               0,0,0,0, 0,0,0,0,  0,0,0,  PVs, SZ, 320, 3*SZ),
            JB(WqTs, SZ, 320, 3*SZ,  WkTs, SZ, 320, 3*SZ,  320, 5, 5, 1.f, 16,
               0,0,0,0, 0,0,0,0,  0,0,0,  KQTs, SZ, 320, 3*SZ),
            JB(WkTs, SZ, 320, 3*SZ,  WqTs, SZ, 320, 3*SZ,  320, 5, 5, 1.f, 16,
               0,0,0,0, 0,0,0,0,  0,0,0,  KQs, SZ, 320, 3*SZ)};
        int nb[4] = {160, 75, 75, 75};
        fire(js, nb, 4);
    }
    // 5) LG: Gmid = T1[:,64:192]*E^T | G band col copies (Ci = T1s splits)
    {
        CJob js[3] = {
            JB(T1s + 64, SZ, 320, 16*SZ,  embs, 0, 128, 16384,  128, 5, 2, 1.f, 16,
               0,0,0,0, 0,0,0,0,  0,0,0,  Gs + 64, SZ, 320, 16*SZ),
            JB(0,0,0,0, 0,0,0,0,  0, 5, 1, 0.f, 32|16,
               T1s, SZ, 320, 16*SZ, 0,0,0,0,  0,0,0,  Gs, SZ, 320, 16*SZ),
            JB(0,0,0,0, 0,0,0,0,  0, 5, 2, 0.f, 32|16,
               T1s + 192, SZ, 320, 16*SZ, 0,0,0,0,  0,0,0,  Gs + 192, SZ, 320, 16*SZ)};
        int nb[3] = {160, 80, 160};
        fire(js, nb, 3);
    }
    // 6..13) layers: X = PV*G; Zt = G*KQ^T; A = c*X*KQ (+A^T); U = c*X*Zt^T;
    //         G' = U*A^T + G + U + U^T
    for (int l = 0; l < 3; ++l) {
        const ushort* PVl = PVs + (ll)l * SZ;
        const ushort* KQTl = KQTs + (ll)l * SZ;
        const ushort* KQl = KQs + (ll)l * SZ;
        ushort* ATl = ATs + (ll)l * 16 * SZ;
        if (l < 2) {
            CJob s1[2] = {
                JB(PVl, 0, 320, 3*SZ,  Gs, SZ, 320, 16*SZ,  320, 5, 5, 1.f, 16,
                   0,0,0,0, 0,0,0,0,  0,0,0,  Xs, SZ, 320, 16*SZ),
                JB(Gs, SZ, 320, 16*SZ,  KQl, 0, 320, 3*SZ,  320, 5, 5, 1.f, 16,
                   0,0,0,0, 0,0,0,0,  0,0,0,  Zts, SZ, 320, 16*SZ)};
            int n1[2] = {400, 400};
            fire(s1, n1, 2);
            CJob s2[3] = {
                JB(Xs, SZ, 320, 16*SZ,  KQTl, 0, 320, 3*SZ,  320, 5, 5, cinv, 16,
                   0,0,0,0, 0,0,0,0,  0,0,0,  As, SZ, 320, 16*SZ),
                JB(KQTl, 0, 320, 3*SZ,  Xs, SZ, 320, 16*SZ,  320, 5, 5, cinv, 16,
                   0,0,0,0, 0,0,0,0,  0,0,0,  ATl, SZ, 320, 48*SZ),
                JB(Xs, SZ, 320, 16*SZ,  Zts, SZ, 320, 16*SZ,  320, 5, 5, cinv, 16,
                   0,0,0,0, 0,0,0,0,  0,0,0,  Us, SZ, 320, 16*SZ)};
            int n2[3] = {400, 400, 400};
            fire(s2, n2, 3);
            CJob s3[1] = {
                JB(Us, SZ, 320, 16*SZ,  As, SZ, 320, 16*SZ,  320, 5, 5, 1.f, 16|32|2|4|64,
                   Gs, SZ, 320, 16*SZ,  Us, SZ, 320, 16*SZ,  0,0,0,  Gs, SZ, 320, 16*SZ)};
            int n3[1] = {400};
            fire(s3, n3, 1);
        } else {
            CJob s1[1] = {
                JB(PVl, 0, 320, 3*SZ,  Gs, SZ, 320, 16*SZ,  320, 5, 5, 1.f, 16,
                   0,0,0,0, 0,0,0,0,  0,0,0,  Xs, SZ, 320, 16*SZ)};
            int n1[1] = {400};
            fire(s1, n1, 1);
            CJob s2[1] = {
                JB(KQTl, 0, 320, 3*SZ,  Xs, SZ, 320, 16*SZ,  320, 5, 5, cinv, 16,
                   0,0,0,0, 0,0,0,0,  0,0,0,  ATl, SZ, 320, 48*SZ)};
            int n2[1] = {400};
            fire(s2, n2, 1);
        }
    }
    // 14) q1 = q0 + E^T * A2[192:,:]   (K=128, Ci fp32 shared)
    {
        CJob js[1] = {
            JB(embTs, 0, 128, 16384,  ATs + 2*16*SZ + 192, SZ, 320, 48*SZ,  128, 2, 5, 1.f, 1|16,
               q0f, 0, 320, 0, 0,0,0,0,  0,0,0,  q1s, RS, 320, 16*RS)};
        int nb[1] = {160};
        fire(js, nb, 1);
    }
    // 15) q2 = q1 + q1*A1   (Ci = q1 splits)
    {
        CJob js[1] = {
            JB(q1s, RS, 320, 16*RS,  ATs + 1*16*SZ, SZ, 320, 48*SZ,  320, 2, 5, 1.f, 32|16,
               q1s, RS, 320, 16*RS, 0,0,0,0,  0,0,0,  q2s, RS, 320, 16*RS)};
        int nb[1] = {160};
        fire(js, nb, 1);
    }
    // 16) q3 = q2 + q2*A0
    {
        CJob js[1] = {
            JB(q2s, RS, 320, 16*RS,  ATs, SZ, 320, 48*SZ,  320, 2, 5, 1.f, 32|16,
               q2s, RS, 320, 16*RS, 0,0,0,0,  0,0,0,  q3s, RS, 320, 16*RS)};
        int nb[1] = {160};
        fire(js, nb, 1);
    }
    // 17) LB = q3*W : mid mfma + band copies (Ci = q3 splits)
    {
        CJob js[3] = {
            JB(q3s + 64, RS, 320, 16*RS,  embTs, 0, 128, 16384,  128, 2, 2, 1.f, 16,
               0,0,0,0, 0,0,0,0,  0,0,0,  LBs + 64, RS, 320, 16*RS),
            JB(0,0,0,0, 0,0,0,0,  0, 2, 1, 0.f, 32|16,
               q3s, RS, 320, 16*RS, 0,0,0,0,  0,0,0,  LBs, RS, 320, 16*RS),
            JB(0,0,0,0, 0,0,0,0,  0, 2, 2, 0.f, 32|16,
               q3s + 192, RS, 320, 16*RS, 0,0,0,0,  0,0,0,  LBs + 192, RS, 320, 16*RS)};
        int nb[3] = {64, 32, 64};
        fire(js, nb, 3);
    }
    // 18) logits + softmax (MFMA)
    logits_mfma_k<<<dim3(32, 16), 256, 0, stream>>>(x, LBs, logits, pred);
}

// Round 8
// 320.620 us; speedup vs baseline: 1.7137x; 1.7137x over previous
//
#include <hip/hip_runtime.h>
#include <math.h>

typedef long long ll;
typedef unsigned int uint;
typedef unsigned short ushort;
typedef __attribute__((ext_vector_type(4))) float f32x4;
typedef __attribute__((ext_vector_type(8))) short bf16x8;

#define SZ 102400LL
#define RS 40960LL

// split fp32 -> hi/lo bf16 (RNE both)
__device__ inline void split2(float v, ushort& h, ushort& l)
{
    uint u = __float_as_uint(v);
    uint uh = u + (0x7FFFu + ((u >> 16) & 1u));
    h = (ushort)(uh >> 16);
    float hf = __uint_as_float((uint)h << 16);
    float d = v - hf;
    uint ud = __float_as_uint(d);
    l = (ushort)((ud + (0x7FFFu + ((ud >> 16) & 1u))) >> 16);
}
__device__ inline float us2f(ushort h, ushort l)
{
    return __uint_as_float((uint)h << 16) + __uint_as_float((uint)l << 16);
}

// ---------------------------------------------------------------------------
// setup: transpose-splits of Wq/Wk/Wv (per layer), plain split P, emb splits
// (plain + transposed), q0 build. 407 blocks.
// ---------------------------------------------------------------------------
__global__ __launch_bounds__(256) void sp_k(
    const float* __restrict__ Wq, const float* __restrict__ Wk,
    const float* __restrict__ Wv, const float* __restrict__ P,
    const float* __restrict__ emb,
    ushort* __restrict__ WqTs, ushort* __restrict__ WkTs, ushort* __restrict__ WvTs,
    ushort* __restrict__ Ps, ushort* __restrict__ embs, ushort* __restrict__ embTs,
    float* __restrict__ q0)
{
    int bid = blockIdx.x, tid = threadIdx.x;
    if (bid < 225) {                       // transpose-split 320x320 mats
        int m = bid / 25, t = bid % 25;
        const float* mats[3] = {Wq, Wk, Wv};
        ushort* dsts[3] = {WqTs, WkTs, WvTs};
        const float* src = mats[m / 3] + (ll)(m % 3) * SZ;
        ushort* dst = dsts[m / 3] + (ll)(m % 3) * SZ;
        int r0 = (t / 5) * 64, c0 = (t % 5) * 64;
        __shared__ float T[64][65];
        #pragma unroll
        for (int s = 0; s < 4; ++s) {      // load 64x64 tile: 1024 float4
            int idx = s * 256 + tid;
            int r = idx >> 4, cq = (idx & 15) * 4;
            *(float4*)&T[r][cq] = *(const float4*)(src + (ll)(r0 + r) * 320 + c0 + cq);
        }
        __syncthreads();
        {                                  // store: 256 items (c, kq) x 16 k each
            int c = tid >> 2, kq = (tid & 3) * 16;
            bf16x8 h0, h1, l0, l1;
            #pragma unroll
            for (int u = 0; u < 8; ++u) {
                ushort h, l;
                split2(T[kq + u][c], h, l);     h0[u] = (short)h; l0[u] = (short)l;
                split2(T[kq + 8 + u][c], h, l); h1[u] = (short)h; l1[u] = (short)l;
            }
            ushort* dh = dst + (ll)(c0 + c) * 320 + r0 + kq;
            *(bf16x8*)dh = h0; *(bf16x8*)(dh + 8) = h1;
            *(bf16x8*)(dh + 3 * SZ) = l0; *(bf16x8*)(dh + 3 * SZ + 8) = l1;
        }
    } else if (bid < 375) {                // plain split P (3*SZ)
        ll off = (ll)(bid - 225) * 2048 + tid * 8;
        float4 v0 = *(const float4*)(P + off);
        float4 v1 = *(const float4*)(P + off + 4);
        float vals[8] = {v0.x,v0.y,v0.z,v0.w,v1.x,v1.y,v1.z,v1.w};
        bf16x8 hv, lv;
        #pragma unroll
        for (int u = 0; u < 8; ++u) { ushort h,l; split2(vals[u],h,l);
                                      hv[u]=(short)h; lv[u]=(short)l; }
        *(bf16x8*)(Ps + off) = hv;
        *(bf16x8*)(Ps + off + 3 * SZ) = lv;
    } else if (bid < 383) {                // plain split emb (16384)
        ll off = (ll)(bid - 375) * 2048 + tid * 8;
        float4 v0 = *(const float4*)(emb + off);
        float4 v1 = *(const float4*)(emb + off + 4);
        float vals[8] = {v0.x,v0.y,v0.z,v0.w,v1.x,v1.y,v1.z,v1.w};
        bf16x8 hv, lv;
        #pragma unroll
        for (int u = 0; u < 8; ++u) { ushort h,l; split2(vals[u],h,l);
                                      hv[u]=(short)h; lv[u]=(short)l; }
        *(bf16x8*)(embs + off) = hv;
        *(bf16x8*)(embs + off + 16384) = lv;
    } else if (bid < 387) {                // transpose-split emb -> embTs
        int t = bid - 383;
        int r0 = (t >> 1) * 64, c0 = (t & 1) * 64;
        __shared__ float T[64][65];
        {
            int r = tid >> 2, cq = (tid & 3) * 4;
            *(float4*)&T[r][cq]      = *(const float4*)(emb + (ll)(r0 + r) * 128 + c0 + cq);
            *(float4*)&T[r][cq + 16] = *(const float4*)(emb + (ll)(r0 + r) * 128 + c0 + cq + 16);
            *(float4*)&T[r][cq + 32] = *(const float4*)(emb + (ll)(r0 + r) * 128 + c0 + cq + 32);
            *(float4*)&T[r][cq + 48] = *(const float4*)(emb + (ll)(r0 + r) * 128 + c0 + cq + 48);
        }
        __syncthreads();
        {
            int c = tid >> 2, kq = (tid & 3) * 16;
            bf16x8 h0, h1, l0, l1;
            #pragma unroll
            for (int u = 0; u < 8; ++u) {
                ushort h, l;
                split2(T[kq + u][c], h, l);     h0[u]=(short)h; l0[u]=(short)l;
                split2(T[kq + 8 + u][c], h, l); h1[u]=(short)h; l1[u]=(short)l;
            }
            ushort* dh = embTs + (ll)(c0 + c) * 128 + r0 + kq;
            *(bf16x8*)dh = h0; *(bf16x8*)(dh + 8) = h1;
            *(bf16x8*)(dh + 16384) = l0; *(bf16x8*)(dh + 16384 + 8) = l1;
        }
    } else {                               // q0[c][i]
        ll base = (ll)(bid - 387) * 2048;
        #pragma unroll
        for (int s = 0; s < 8; ++s) {
            ll id = base + s * 256 + tid;
            int c = (int)(id / 320), i = (int)(id % 320);
            q0[id] = (i >= 192) ? emb[(ll)(i - 192) * 128 + c] : 0.f;
        }
    }
}

// ---------------------------------------------------------------------------
// Gram via MFMA (verified): part[p][b][t], 960 blocks, XCD-swizzled.
// ---------------------------------------------------------------------------
__global__ __launch_bounds__(256) void gram_mfma_k(const float* __restrict__ x,
                                                   float* __restrict__ part)
{
    int flat = blockIdx.x;
    int swz = (flat & 7) * 120 + (flat >> 3);
    int b = swz / 60;
    int rr = swz - b * 60;
    int p = rr / 15, t = rr - p * 15;
    int ti = 0, rem = t;
    while (rem >= 5 - ti) { rem -= 5 - ti; ++ti; }
    int tj = ti + rem;
    int i0 = ti * 64, j0 = tj * 64;
    bool diag = (ti == tj);
    const float* X = x + (ll)b * 320 * 2048;
    __shared__ __align__(16) ushort Ah[64 * 40], Al_[64 * 40], Bh[64 * 40], Bl_[64 * 40];
    int tid = threadIdx.x;
    int wv = tid >> 6, lane = tid & 63;
    int lr = lane & 15, kb = (lane >> 4) * 8;
    int cr = tid >> 2, ck = (tid & 3) * 8;
    f32x4 hh[4], hl[4], lh[4];
    f32x4 zz = {0.f, 0.f, 0.f, 0.f};
    #pragma unroll
    for (int f = 0; f < 4; ++f) { hh[f] = zz; hl[f] = zz; lh[f] = zz; }
    const ushort* BhS = diag ? Ah : Bh;
    const ushort* BlS = diag ? Al_ : Bl_;

    for (int it = 0; it < 16; ++it) {
        int kg0 = p * 512 + it * 32;
        {
            const float* src = X + (ll)(i0 + cr) * 2048 + kg0 + ck;
            float4 v0 = *(const float4*)src;
            float4 v1 = *(const float4*)(src + 4);
            float vals[8] = {v0.x,v0.y,v0.z,v0.w,v1.x,v1.y,v1.z,v1.w};
            if (kg0 + ck + 7 >= 2047) {
                #pragma unroll
                for (int u = 0; u < 8; ++u) if (kg0 + ck + u >= 2047) vals[u] = 0.f;
            }
            bf16x8 hv, lv;
            #pragma unroll
            for (int u = 0; u < 8; ++u) { ushort h, l; split2(vals[u], h, l);
                                          hv[u] = (short)h; lv[u] = (short)l; }
            *(bf16x8*)&Ah[cr * 40 + ck] = hv;
            *(bf16x8*)&Al_[cr * 40 + ck] = lv;
        }
        if (!diag) {
            const float* src = X + (ll)(j0 + cr) * 2048 + kg0 + ck;
            float4 v0 = *(const float4*)src;
            float4 v1 = *(const float4*)(src + 4);
            float vals[8] = {v0.x,v0.y,v0.z,v0.w,v1.x,v1.y,v1.z,v1.w};
            if (kg0 + ck + 7 >= 2047) {
                #pragma unroll
                for (int u = 0; u < 8; ++u) if (kg0 + ck + u >= 2047) vals[u] = 0.f;
            }
            bf16x8 hv, lv;
            #pragma unroll
            for (int u = 0; u < 8; ++u) { ushort h, l; split2(vals[u], h, l);
                                          hv[u] = (short)h; lv[u] = (short)l; }
            *(bf16x8*)&Bh[cr * 40 + ck] = hv;
            *(bf16x8*)&Bl_[cr * 40 + ck] = lv;
        }
        __syncthreads();
        bf16x8 ah = *(const bf16x8*)&Ah[(wv * 16 + lr) * 40 + kb];
        bf16x8 al = *(const bf16x8*)&Al_[(wv * 16 + lr) * 40 + kb];
        #pragma unroll
        for (int f = 0; f < 4; ++f) {
            bf16x8 bh_ = *(const bf16x8*)&BhS[(f * 16 + lr) * 40 + kb];
            bf16x8 bl_ = *(const bf16x8*)&BlS[(f * 16 + lr) * 40 + kb];
            hh[f] = __builtin_amdgcn_mfma_f32_16x16x32_bf16(ah, bh_, hh[f], 0, 0, 0);
            hl[f] = __builtin_amdgcn_mfma_f32_16x16x32_bf16(ah, bl_, hl[f], 0, 0, 0);
            lh[f] = __builtin_amdgcn_mfma_f32_16x16x32_bf16(al, bh_, lh[f], 0, 0, 0);
        }
        __syncthreads();
    }
    float* out = part + (((ll)p * 16 + b) * 15 + t) * 4096;
    int orow0 = wv * 16 + (lane >> 4) * 4;
    #pragma unroll
    for (int f = 0; f < 4; ++f) {
        int col = f * 16 + lr;
        #pragma unroll
        for (int r = 0; r < 4; ++r)
            out[(orow0 + r) * 64 + col] = hh[f][r] + hl[f][r] + lh[f][r];
    }
}

// Sum 4 partials; write GxS splits (both triangles) + T1s splits for the
// identity-band rows (0:64, 192:320). Grid 240.
__global__ __launch_bounds__(256) void gram_red_k(const float* __restrict__ part,
                                                  ushort* __restrict__ GxS,
                                                  ushort* __restrict__ T1s)
{
    int bt = blockIdx.x;
    int b = bt / 15, t = bt % 15;
    int ti = 0, rem = t;
    while (rem >= 5 - ti) { rem -= 5 - ti; ++ti; }
    int tj = ti + rem;
    int i0 = ti * 64, j0 = tj * 64;
    int tid = threadIdx.x;
    int tx = tid & 15, rg = tid >> 4;
    bool wi = (ti == 0 || ti >= 3);
    bool wj = (tj == 0 || tj >= 3);
    ushort* Gb = GxS + (ll)b * SZ;
    ushort* Tsb = T1s + (ll)b * SZ;
    #pragma unroll
    for (int m = 0; m < 4; ++m) {
        int r = rg * 4 + m;
        float s[4] = {};
        for (int p = 0; p < 4; ++p) {
            const float* src = part + (((ll)p * 16 + b) * 15 + t) * 4096 + r * 64 + tx * 4;
            float4 v = *(const float4*)src;
            s[0]+=v.x; s[1]+=v.y; s[2]+=v.z; s[3]+=v.w;
        }
        #pragma unroll
        for (int u = 0; u < 4; ++u) {
            ushort h, l; split2(s[u], h, l);
            ll rd = (ll)(i0 + r) * 320 + j0 + tx * 4 + u;
            ll rt = (ll)(j0 + tx * 4 + u) * 320 + (i0 + r);
            Gb[rd] = h; Gb[rd + 16 * SZ] = l;
            Gb[rt] = h; Gb[rt + 16 * SZ] = l;
            if (wi) { Tsb[rd] = h; Tsb[rd + 16 * SZ] = l; }
            if (wj) { Tsb[rt] = h; Tsb[rt + 16 * SZ] = l; }
        }
    }
}

// ---------------------------------------------------------------------------
// Packed MFMA bf16x3 job kernel v2: XCD-batch-grouped swizzle + LDS-staged B
// (double-buffered, 64x40-padded) + reg-prefetched A.
// C[bz](MxN) = alpha * A . BL^T + adds.  K==0 -> copy epilogue.
// flags: 1 +Ci fp32 | 32 +Ci split-pair | 2 +Ci2 | 4 +Ci2^T (64: Ci2 is
// split-pair for both 2 and 4) | 8 write C fp32 | 16 write Cs splits.
// ---------------------------------------------------------------------------
struct CJob {
    const ushort *Ah, *Bh;
    const void *Ci, *Ci2;
    float* C; ushort* Cs;
    ll aB, bB, ciB, ci2B, cB, csB;
    ll aLo, bLo, csLo, ciLo, ci2Lo;
    int aS, bS, ciS, ci2S, cS, csS;
    int K, tN, tpb, flags;
    int swzQ, swzR;
    float alpha;
};
struct CPack { CJob j[4]; };

__global__ __launch_bounds__(256) void mchain_k(CPack jp, int c0, int c1, int c2)
{
    int bid = blockIdx.x;
    int ji, local;
    if (bid < c0)      { ji = 0; local = bid; }
    else if (bid < c1) { ji = 1; local = bid - c0; }
    else if (bid < c2) { ji = 2; local = bid - c1; }
    else               { ji = 3; local = bid - c2; }
    CJob j = jp.j[ji];
    // bijective XCD-grouping swizzle (m204): batches contiguous per XCD chunk
    int xcd = local & 7, sidx = local >> 3;
    int base = (xcd < j.swzR) ? xcd * (j.swzQ + 1)
                              : j.swzR * (j.swzQ + 1) + (xcd - j.swzR) * j.swzQ;
    int swz = base + sidx;
    int bz = swz / j.tpb;
    int t = swz - bz * j.tpb;
    int i0 = (t / j.tN) * 64, j0 = (t % j.tN) * 64;
    int tid = threadIdx.x;
    int wv = tid >> 6, lane = tid & 63;
    int lr = lane & 15, kb = (lane >> 4) * 8;
    f32x4 hh[4], cx[4];
    f32x4 zz = {0.f,0.f,0.f,0.f};
    #pragma unroll
    for (int f = 0; f < 4; ++f) { hh[f] = zz; cx[f] = zz; }

    __shared__ __align__(16) ushort Bsh[2][2][2560];   // [buf][plane][row*40+k]

    if (j.K > 0) {
        int srow = tid >> 2, skq = (tid & 3) * 8;
        const ushort* Bg = j.Bh + (ll)bz * j.bB + (ll)(j0 + srow) * j.bS + skq;
        const ushort* Ar = j.Ah + (ll)bz * j.aB + (ll)(i0 + wv * 16 + lr) * j.aS + kb;
        bf16x8 svh, svl, ah, al, ahn, aln;
        // prologue: stage k-step 0
        svh = *(const bf16x8*)Bg;
        svl = *(const bf16x8*)(Bg + j.bLo);
        *(bf16x8*)&Bsh[0][0][srow * 40 + skq] = svh;
        *(bf16x8*)&Bsh[0][1][srow * 40 + skq] = svl;
        ah = *(const bf16x8*)Ar;
        al = *(const bf16x8*)(Ar + j.aLo);
        __syncthreads();
        int nit = j.K >> 5;
        for (int it = 0; it < nit; ++it) {
            int cur = it & 1;
            bool more = (it + 1 < nit);
            if (more) {                      // prefetch next k-step (global)
                int k1 = (it + 1) << 5;
                svh = *(const bf16x8*)(Bg + k1);
                svl = *(const bf16x8*)(Bg + j.bLo + k1);
                ahn = *(const bf16x8*)(Ar + k1);
                aln = *(const bf16x8*)(Ar + j.aLo + k1);
            }
            #pragma unroll
            for (int f = 0; f < 4; ++f) {
                bf16x8 bh = *(const bf16x8*)&Bsh[cur][0][(f * 16 + lr) * 40 + kb];
                bf16x8 bl = *(const bf16x8*)&Bsh[cur][1][(f * 16 + lr) * 40 + kb];
                hh[f] = __builtin_amdgcn_mfma_f32_16x16x32_bf16(ah, bh, hh[f], 0, 0, 0);
                cx[f] = __builtin_amdgcn_mfma_f32_16x16x32_bf16(ah, bl, cx[f], 0, 0, 0);
                cx[f] = __builtin_amdgcn_mfma_f32_16x16x32_bf16(al, bh, cx[f], 0, 0, 0);
            }
            if (more) {
                *(bf16x8*)&Bsh[cur ^ 1][0][srow * 40 + skq] = svh;
                *(bf16x8*)&Bsh[cur ^ 1][1][srow * 40 + skq] = svl;
                ah = ahn; al = aln;
            }
            __syncthreads();
        }
    }
    const float* Cif = (const float*)j.Ci;
    const ushort* Ciu = (const ushort*)j.Ci;
    const float* Ci2f = (const float*)j.Ci2;
    const ushort* Ci2u = (const ushort*)j.Ci2;
    float* Cp = j.C + (ll)bz * j.cB;
    ushort* Csp = j.Cs + (ll)bz * j.csB;
    int r0 = i0 + wv * 16 + ((lane >> 4) << 2);
    #pragma unroll
    for (int f = 0; f < 4; ++f) {
        int col = j0 + f * 16 + lr;
        #pragma unroll
        for (int r = 0; r < 4; ++r) {
            int row = r0 + r;
            float v = j.alpha * (hh[f][r] + cx[f][r]);
            if (j.flags & 1)
                v += Cif[(ll)bz * j.ciB + (ll)row * j.ciS + col];
            if (j.flags & 32) {
                const ushort* p = Ciu + (ll)bz * j.ciB + (ll)row * j.ciS + col;
                v += us2f(p[0], p[j.ciLo]);
            }
            if (j.flags & 64) {
                const ushort* b2 = Ci2u + (ll)bz * j.ci2B;
                if (j.flags & 2) { const ushort* p = b2 + (ll)row * j.ci2S + col;
                                   v += us2f(p[0], p[j.ci2Lo]); }
                if (j.flags & 4) { const ushort* p = b2 + (ll)col * j.ci2S + row;
                                   v += us2f(p[0], p[j.ci2Lo]); }
            } else {
                if (j.flags & 2) v += Ci2f[(ll)bz * j.ci2B + (ll)row * j.ci2S + col];
                if (j.flags & 4) v += Ci2f[(ll)bz * j.ci2B + (ll)col * j.ci2S + row];
            }
            if (j.flags & 8) Cp[(ll)row * j.cS + col] = v;
            if (j.flags & 16) {
                ushort h, l; split2(v, h, l);
                ushort* p = Csp + (ll)row * j.csS + col;
                p[0] = h; p[j.csLo] = l;
            }
        }
    }
}

// ---------------------------------------------------------------------------
// MFMA logits + softmax. Grid (32, 16), 256 thr.
// ---------------------------------------------------------------------------
__global__ __launch_bounds__(256) void logits_mfma_k(const float* __restrict__ x,
                                                     const ushort* __restrict__ LBs,
                                                     float* __restrict__ logits,
                                                     float* __restrict__ pred)
{
    int b = blockIdx.y;
    int i0 = blockIdx.x * 64;
    const float* X = x + (ll)b * 320 * 2048;
    const ushort* LB = LBs + (ll)b * RS;
    __shared__ float Xs_[2][32][68];
    int tid = threadIdx.x;
    int wv = tid >> 6, lane = tid & 63;
    int lr = lane & 15, kb = (lane >> 4) * 8;
    int lkk = tid >> 3, lq = tid & 7;
    f32x4 hh[8], cx[8];
    f32x4 zz = {0.f,0.f,0.f,0.f};
    #pragma unroll
    for (int f = 0; f < 8; ++f) { hh[f] = zz; cx[f] = zz; }
    float4 p0, p1;
    auto glb = [&](int k0) {
        const float* s = X + (ll)(k0 + lkk) * 2048 + i0 + lq * 8;
        p0 = *(const float4*)s; p1 = *(const float4*)(s + 4);
    };
    auto stl = [&](int buf) {
        *(float4*)&Xs_[buf][lkk][lq * 8] = p0;
        *(float4*)&Xs_[buf][lkk][lq * 8 + 4] = p1;
    };
    glb(0); stl(0);
    __syncthreads();
    for (int it = 0; it < 10; ++it) {
        int cur = it & 1;
        if (it < 9) glb((it + 1) * 32);
        bf16x8 ah, al;
        #pragma unroll
        for (int u = 0; u < 8; ++u) {
            ushort h, l;
            split2(Xs_[cur][kb + u][wv * 16 + lr], h, l);
            ah[u] = (short)h; al[u] = (short)l;
        }
        #pragma unroll
        for (int f = 0; f < 8; ++f) {
            const ushort* Bp = LB + (ll)(f * 16 + lr) * 320 + it * 32 + kb;
            bf16x8 bh = *(const bf16x8*)Bp;
            bf16x8 bl = *(const bf16x8*)(Bp + 16 * RS);
            hh[f] = __builtin_amdgcn_mfma_f32_16x16x32_bf16(ah, bh, hh[f], 0, 0, 0);
            cx[f] = __builtin_amdgcn_mfma_f32_16x16x32_bf16(ah, bl, cx[f], 0, 0, 0);
            cx[f] = __builtin_amdgcn_mfma_f32_16x16x32_bf16(al, bh, cx[f], 0, 0, 0);
        }
        if (it < 9) stl(cur ^ 1);
        __syncthreads();
    }
    #pragma unroll
    for (int r = 0; r < 4; ++r) {
        int n = i0 + wv * 16 + ((lane >> 4) << 2) + r;
        float v[8];
        float mx = -1e30f;
        #pragma unroll
        for (int f = 0; f < 8; ++f) { v[f] = hh[f][r] + cx[f][r]; mx = fmaxf(mx, v[f]); }
        #pragma unroll
        for (int off = 8; off; off >>= 1) mx = fmaxf(mx, __shfl_xor(mx, off));
        float e[8], sm = 0.f;
        #pragma unroll
        for (int f = 0; f < 8; ++f) { e[f] = expf(v[f] - mx); sm += e[f]; }
        #pragma unroll
        for (int off = 8; off; off >>= 1) sm += __shfl_xor(sm, off);
        float inv = 1.f / sm;
        ll ro = ((ll)b * 2048 + n) * 128 + lr;
        #pragma unroll
        for (int f = 0; f < 8; ++f) {
            logits[ro + f * 16] = v[f];
            pred[ro + f * 16] = e[f] * inv;
        }
    }
}

extern "C" void kernel_launch(void* const* d_in, const int* in_sizes, int n_in,
                              void* d_out, int out_size, void* d_ws, size_t ws_size,
                              hipStream_t stream)
{
    const float* x   = (const float*)d_in[0];
    const float* emb = (const float*)d_in[1];
    const float* Wq  = (const float*)d_in[2];
    const float* Wk  = (const float*)d_in[3];
    const float* Wv  = (const float*)d_in[4];
    const float* P   = (const float*)d_in[5];

    float* logits = (float*)d_out;
    float* pred   = logits + (ll)16 * 2048 * 128;

    float* w = (float*)d_ws;
    auto takef = [&](ll n) { float* p = w; w += n; return p; };
    ushort* GxS  = (ushort*)takef(16 * SZ); // alias: Xs (after LA)
    ushort* T1s  = (ushort*)takef(16 * SZ); // alias: Zts (after LG)
    ushort* Gs   = (ushort*)takef(16 * SZ);
    ushort* As   = (ushort*)takef(16 * SZ);
    ushort* Us   = (ushort*)takef(16 * SZ);
    float*  ATsF = takef(48 * SZ);          // part aliases front (3.93M < 4.92M)
    ushort* ATs  = (ushort*)ATsF;
    ushort* PVs  = (ushort*)takef(3 * SZ);
    ushort* KQTs = (ushort*)takef(3 * SZ);
    ushort* KQs  = (ushort*)takef(3 * SZ);
    ushort* Ps   = (ushort*)takef(3 * SZ);
    ushort* WqTs = (ushort*)takef(3 * SZ);
    ushort* WkTs = (ushort*)takef(3 * SZ);
    ushort* WvTs = (ushort*)takef(3 * SZ);
    ushort* embs = (ushort*)takef(16384);
    ushort* embTs= (ushort*)takef(16384);
    float*  q0f  = takef(RS);
    ushort* q1s  = (ushort*)takef(16 * RS); // alias: q3s
    ushort* q2s  = (ushort*)takef(16 * RS);
    ushort* LBs  = (ushort*)takef(16 * RS);
    ushort* Xs   = GxS;
    ushort* Zts  = T1s;
    float*  part = ATsF;
    ushort* q3s  = q1s;
    const float cinv = 1.f / 2047.f;

    auto JB = [](const ushort* Ah, ll aB, int aS, ll aLo,
                 const ushort* Bh, ll bB, int bS, ll bLo,
                 int K, int tM, int tN, float alpha, int flags,
                 const void* Ci, ll ciB, int ciS, ll ciLo,
                 const void* Ci2, ll ci2B, int ci2S, ll ci2Lo,
                 float* C, ll cB, int cS,
                 ushort* Cs, ll csB, int csS, ll csLo) {
        CJob j;
        j.Ah = Ah; j.Bh = Bh;
        j.Ci = Ci; j.Ci2 = Ci2; j.C = C; j.Cs = Cs;
        j.aB = aB; j.bB = bB; j.ciB = ciB; j.ci2B = ci2B; j.cB = cB; j.csB = csB;
        j.aLo = aLo; j.bLo = bLo; j.csLo = csLo; j.ciLo = ciLo; j.ci2Lo = ci2Lo;
        j.aS = aS; j.bS = bS; j.ciS = ciS; j.ci2S = ci2S; j.cS = cS; j.csS = csS;
        j.K = K; j.tN = tN; j.tpb = tM * tN; j.flags = flags; j.alpha = alpha;
        j.swzQ = 0; j.swzR = 0;
        return j;
    };
    auto fire = [&](const CJob* js, const int* nb, int n) {
        CPack jp;
        int cum[4], tot = 0;
        for (int i = 0; i < 4; ++i) {
            jp.j[i] = js[i < n ? i : 0];
            if (i < n) { jp.j[i].swzQ = nb[i] >> 3; jp.j[i].swzR = nb[i] & 7; }
            tot += (i < n ? nb[i] : 0);
            cum[i] = tot;
        }
        mchain_k<<<tot, 256, 0, stream>>>(jp, cum[0], cum[1], cum[2]);
    };

    // 1) setup splits
    sp_k<<<407, 256, 0, stream>>>(Wq, Wk, Wv, P, emb,
                                  WqTs, WkTs, WvTs, Ps, embs, embTs, q0f);
    // 2-3) gram
    gram_mfma_k<<<960, 256, 0, stream>>>(x, part);
    gram_red_k<<<240, 256, 0, stream>>>(part, GxS, T1s);
    // 4) LA: T1mid = E*Gx[64:192] | PV = P*Wv | KQT = Wq^T Wk | KQ = Wk^T Wq
    {
        CJob js[4] = {
            JB(embs, 0, 128, 16384,  GxS + 64, SZ, 320, 16*SZ,  128, 2, 5, 1.f, 16,
               0,0,0,0, 0,0,0,0,  0,0,0,  T1s + 64*320, SZ, 320, 16*SZ),
            JB(Ps, SZ, 320, 3*SZ,  WvTs, SZ, 320, 3*SZ,  320, 5, 5, 1.f, 16,
               0,0,0,0, 0,0,0,0,  0,0,0,  PVs, SZ, 320, 3*SZ),
            JB(WqTs, SZ, 320, 3*SZ,  WkTs, SZ, 320, 3*SZ,  320, 5, 5, 1.f, 16,
               0,0,0,0, 0,0,0,0,  0,0,0,  KQTs, SZ, 320, 3*SZ),
            JB(WkTs, SZ, 320, 3*SZ,  WqTs, SZ, 320, 3*SZ,  320, 5, 5, 1.f, 16,
               0,0,0,0, 0,0,0,0,  0,0,0,  KQs, SZ, 320, 3*SZ)};
        int nb[4] = {160, 75, 75, 75};
        fire(js, nb, 4);
    }
    // 5) LG: Gmid = T1[:,64:192]*E^T | G band col copies (Ci = T1s splits)
    {
        CJob js[3] = {
            JB(T1s + 64, SZ, 320, 16*SZ,  embs, 0, 128, 16384,  128, 5, 2, 1.f, 16,
               0,0,0,0, 0,0,0,0,  0,0,0,  Gs + 64, SZ, 320, 16*SZ),
            JB(0,0,0,0, 0,0,0,0,  0, 5, 1, 0.f, 32|16,
               T1s, SZ, 320, 16*SZ, 0,0,0,0,  0,0,0,  Gs, SZ, 320, 16*SZ),
            JB(0,0,0,0, 0,0,0,0,  0, 5, 2, 0.f, 32|16,
               T1s + 192, SZ, 320, 16*SZ, 0,0,0,0,  0,0,0,  Gs + 192, SZ, 320, 16*SZ)};
        int nb[3] = {160, 80, 160};
        fire(js, nb, 3);
    }
    // 6..13) layers: X = PV*G; Zt = G*KQ^T; A = c*X*KQ (+A^T); U = c*X*Zt^T;
    //         G' = U*A^T + G + U + U^T
    for (int l = 0; l < 3; ++l) {
        const ushort* PVl = PVs + (ll)l * SZ;
        const ushort* KQTl = KQTs + (ll)l * SZ;
        const ushort* KQl = KQs + (ll)l * SZ;
        ushort* ATl = ATs + (ll)l * 16 * SZ;
        if (l < 2) {
            CJob s1[2] = {
                JB(PVl, 0, 320, 3*SZ,  Gs, SZ, 320, 16*SZ,  320, 5, 5, 1.f, 16,
                   0,0,0,0, 0,0,0,0,  0,0,0,  Xs, SZ, 320, 16*SZ),
                JB(Gs, SZ, 320, 16*SZ,  KQl, 0, 320, 3*SZ,  320, 5, 5, 1.f, 16,
                   0,0,0,0, 0,0,0,0,  0,0,0,  Zts, SZ, 320, 16*SZ)};
            int n1[2] = {400, 400};
            fire(s1, n1, 2);
            CJob s2[3] = {
                JB(Xs, SZ, 320, 16*SZ,  KQTl, 0, 320, 3*SZ,  320, 5, 5, cinv, 16,
                   0,0,0,0, 0,0,0,0,  0,0,0,  As, SZ, 320, 16*SZ),
                JB(KQTl, 0, 320, 3*SZ,  Xs, SZ, 320, 16*SZ,  320, 5, 5, cinv, 16,
                   0,0,0,0, 0,0,0,0,  0,0,0,  ATl, SZ, 320, 48*SZ),
                JB(Xs, SZ, 320, 16*SZ,  Zts, SZ, 320, 16*SZ,  320, 5, 5, cinv, 16,
                   0,0,0,0, 0,0,0,0,  0,0,0,  Us, SZ, 320, 16*SZ)};
            int n2[3] = {400, 400, 400};
            fire(s2, n2, 3);
            CJob s3[1] = {
                JB(Us, SZ, 320, 16*SZ,  As, SZ, 320, 16*SZ,  320, 5, 5, 1.f, 16|32|2|4|64,
                   Gs, SZ, 320, 16*SZ,  Us, SZ, 320, 16*SZ,  0,0,0,  Gs, SZ, 320, 16*SZ)};
            int n3[1] = {400};
            fire(s3, n3, 1);
        } else {
            CJob s1[1] = {
                JB(PVl, 0, 320, 3*SZ,  Gs, SZ, 320, 16*SZ,  320, 5, 5, 1.f, 16,
                   0,0,0,0, 0,0,0,0,  0,0,0,  Xs, SZ, 320, 16*SZ)};
            int n1[1] = {400};
            fire(s1, n1, 1);
            CJob s2[1] = {
                JB(KQTl, 0, 320, 3*SZ,  Xs, SZ, 320, 16*SZ,  320, 5, 5, cinv, 16,
                   0,0,0,0, 0,0,0,0,  0,0,0,  ATl, SZ, 320, 48*SZ)};
            int n2[1] = {400};
            fire(s2, n2, 1);
        }
    }
    // 14) q1 = q0 + E^T * A2[192:,:]   (K=128, Ci fp32 shared)
    {
        CJob js[1] = {
            JB(embTs, 0, 128, 16384,  ATs + 2*16*SZ + 192, SZ, 320, 48*SZ,  128, 2, 5, 1.f, 1|16,
               q0f, 0, 320, 0, 0,0,0,0,  0,0,0,  q1s, RS, 320, 16*RS)};
        int nb[1] = {160};
        fire(js, nb, 1);
    }
    // 15) q2 = q1 + q1*A1   (Ci = q1 splits)
    {
        CJob js[1] = {
            JB(q1s, RS, 320, 16*RS,  ATs + 1*16*SZ, SZ, 320, 48*SZ,  320, 2, 5, 1.f, 32|16,
               q1s, RS, 320, 16*RS, 0,0,0,0,  0,0,0,  q2s, RS, 320, 16*RS)};
        int nb[1] = {160};
        fire(js, nb, 1);
    }
    // 16) q3 = q2 + q2*A0
    {
        CJob js[1] = {
            JB(q2s, RS, 320, 16*RS,  ATs, SZ, 320, 48*SZ,  320, 2, 5, 1.f, 32|16,
               q2s, RS, 320, 16*RS, 0,0,0,0,  0,0,0,  q3s, RS, 320, 16*RS)};
        int nb[1] = {160};
        fire(js, nb, 1);
    }
    // 17) LB = q3*W : mid mfma + band copies (Ci = q3 splits)
    {
        CJob js[3] = {
            JB(q3s + 64, RS, 320, 16*RS,  embTs, 0, 128, 16384,  128, 2, 2, 1.f, 16,
               0,0,0,0, 0,0,0,0,  0,0,0,  LBs + 64, RS, 320, 16*RS),
            JB(0,0,0,0, 0,0,0,0,  0, 2, 1, 0.f, 32|16,
               q3s, RS, 320, 16*RS, 0,0,0,0,  0,0,0,  LBs, RS, 320, 16*RS),
            JB(0,0,0,0, 0,0,0,0,  0, 2, 2, 0.f, 32|16,
               q3s + 192, RS, 320, 16*RS, 0,0,0,0,  0,0,0,  LBs + 192, RS, 320, 16*RS)};
        int nb[3] = {64, 32, 64};
        fire(js, nb, 3);
    }
    // 18) logits + softmax (MFMA)
    logits_mfma_k<<<dim3(32, 16), 256, 0, stream>>>(x, LBs, logits, pred);
}

// Round 9
// 315.437 us; speedup vs baseline: 1.7419x; 1.0164x over previous
//
#include <hip/hip_runtime.h>
#include <math.h>

typedef long long ll;
typedef unsigned int uint;
typedef unsigned short ushort;
typedef __attribute__((ext_vector_type(4))) float f32x4;
typedef __attribute__((ext_vector_type(8))) short bf16x8;

#define SZ 102400LL
#define RS 40960LL

// split fp32 -> hi/lo bf16 (RNE both)
__device__ inline void split2(float v, ushort& h, ushort& l)
{
    uint u = __float_as_uint(v);
    uint uh = u + (0x7FFFu + ((u >> 16) & 1u));
    h = (ushort)(uh >> 16);
    float hf = __uint_as_float((uint)h << 16);
    float d = v - hf;
    uint ud = __float_as_uint(d);
    l = (ushort)((ud + (0x7FFFu + ((ud >> 16) & 1u))) >> 16);
}
__device__ inline float us2f(ushort h, ushort l)
{
    return __uint_as_float((uint)h << 16) + __uint_as_float((uint)l << 16);
}

// ---------------------------------------------------------------------------
// Fused gram (blocks 0..959) + setup splits (blocks 960..1366). 1367 blocks.
// Shared 20KB smem union keeps gram occupancy.
// ---------------------------------------------------------------------------
__global__ __launch_bounds__(256) void gram_sp_k(
    const float* __restrict__ x, float* __restrict__ part,
    const float* __restrict__ Wq, const float* __restrict__ Wk,
    const float* __restrict__ Wv, const float* __restrict__ P,
    const float* __restrict__ emb,
    ushort* __restrict__ WqTs, ushort* __restrict__ WkTs, ushort* __restrict__ WvTs,
    ushort* __restrict__ Ps, ushort* __restrict__ embs, ushort* __restrict__ embTs,
    float* __restrict__ q0)
{
    __shared__ __align__(16) char smem[20480];
    int bid0 = blockIdx.x, tid = threadIdx.x;
    if (bid0 < 960) {
        // ---------------- gram body (round-5-verified logic) ----------------
        ushort* Ah  = (ushort*)smem;           // 64*40
        ushort* Al_ = Ah + 2560;
        ushort* Bh  = Al_ + 2560;
        ushort* Bl_ = Bh + 2560;
        int flat = bid0;
        int swz = (flat & 7) * 120 + (flat >> 3);
        int b = swz / 60;
        int rr = swz - b * 60;
        int p = rr / 15, t = rr - p * 15;
        int ti = 0, rem = t;
        while (rem >= 5 - ti) { rem -= 5 - ti; ++ti; }
        int tj = ti + rem;
        int i0 = ti * 64, j0 = tj * 64;
        bool diag = (ti == tj);
        const float* X = x + (ll)b * 320 * 2048;
        int wv = tid >> 6, lane = tid & 63;
        int lr = lane & 15, kb = (lane >> 4) * 8;
        int cr = tid >> 2, ck = (tid & 3) * 8;
        f32x4 hh[4], hl[4], lh[4];
        f32x4 zz = {0.f, 0.f, 0.f, 0.f};
        #pragma unroll
        for (int f = 0; f < 4; ++f) { hh[f] = zz; hl[f] = zz; lh[f] = zz; }
        const ushort* BhS = diag ? Ah : Bh;
        const ushort* BlS = diag ? Al_ : Bl_;

        for (int it = 0; it < 16; ++it) {
            int kg0 = p * 512 + it * 32;
            {
                const float* src = X + (ll)(i0 + cr) * 2048 + kg0 + ck;
                float4 v0 = *(const float4*)src;
                float4 v1 = *(const float4*)(src + 4);
                float vals[8] = {v0.x,v0.y,v0.z,v0.w,v1.x,v1.y,v1.z,v1.w};
                if (kg0 + ck + 7 >= 2047) {
                    #pragma unroll
                    for (int u = 0; u < 8; ++u) if (kg0 + ck + u >= 2047) vals[u] = 0.f;
                }
                bf16x8 hv, lv;
                #pragma unroll
                for (int u = 0; u < 8; ++u) { ushort h, l; split2(vals[u], h, l);
                                              hv[u] = (short)h; lv[u] = (short)l; }
                *(bf16x8*)&Ah[cr * 40 + ck] = hv;
                *(bf16x8*)&Al_[cr * 40 + ck] = lv;
            }
            if (!diag) {
                const float* src = X + (ll)(j0 + cr) * 2048 + kg0 + ck;
                float4 v0 = *(const float4*)src;
                float4 v1 = *(const float4*)(src + 4);
                float vals[8] = {v0.x,v0.y,v0.z,v0.w,v1.x,v1.y,v1.z,v1.w};
                if (kg0 + ck + 7 >= 2047) {
                    #pragma unroll
                    for (int u = 0; u < 8; ++u) if (kg0 + ck + u >= 2047) vals[u] = 0.f;
                }
                bf16x8 hv, lv;
                #pragma unroll
                for (int u = 0; u < 8; ++u) { ushort h, l; split2(vals[u], h, l);
                                              hv[u] = (short)h; lv[u] = (short)l; }
                *(bf16x8*)&Bh[cr * 40 + ck] = hv;
                *(bf16x8*)&Bl_[cr * 40 + ck] = lv;
            }
            __syncthreads();
            bf16x8 ah = *(const bf16x8*)&Ah[(wv * 16 + lr) * 40 + kb];
            bf16x8 al = *(const bf16x8*)&Al_[(wv * 16 + lr) * 40 + kb];
            #pragma unroll
            for (int f = 0; f < 4; ++f) {
                bf16x8 bh_ = *(const bf16x8*)&BhS[(f * 16 + lr) * 40 + kb];
                bf16x8 bl_ = *(const bf16x8*)&BlS[(f * 16 + lr) * 40 + kb];
                hh[f] = __builtin_amdgcn_mfma_f32_16x16x32_bf16(ah, bh_, hh[f], 0, 0, 0);
                hl[f] = __builtin_amdgcn_mfma_f32_16x16x32_bf16(ah, bl_, hl[f], 0, 0, 0);
                lh[f] = __builtin_amdgcn_mfma_f32_16x16x32_bf16(al, bh_, lh[f], 0, 0, 0);
            }
            __syncthreads();
        }
        float* out = part + (((ll)p * 16 + b) * 15 + t) * 4096;
        int orow0 = wv * 16 + (lane >> 4) * 4;
        #pragma unroll
        for (int f = 0; f < 4; ++f) {
            int col = f * 16 + lr;
            #pragma unroll
            for (int r = 0; r < 4; ++r)
                out[(orow0 + r) * 64 + col] = hh[f][r] + hl[f][r] + lh[f][r];
        }
        return;
    }
    // ---------------- setup-splits body (round-8-verified logic) ----------------
    int bid = bid0 - 960;                  // 0..406
    float (*T)[65] = (float(*)[65])smem;   // 64x65 fp32 = 16.6KB <= 20KB
    if (bid < 225) {                       // transpose-split 320x320 mats
        int m = bid / 25, t = bid % 25;
        const float* mats[3] = {Wq, Wk, Wv};
        ushort* dsts[3] = {WqTs, WkTs, WvTs};
        const float* src = mats[m / 3] + (ll)(m % 3) * SZ;
        ushort* dst = dsts[m / 3] + (ll)(m % 3) * SZ;
        int r0 = (t / 5) * 64, c0 = (t % 5) * 64;
        #pragma unroll
        for (int s = 0; s < 4; ++s) {
            int idx = s * 256 + tid;
            int r = idx >> 4, cq = (idx & 15) * 4;
            *(float4*)&T[r][cq] = *(const float4*)(src + (ll)(r0 + r) * 320 + c0 + cq);
        }
        __syncthreads();
        {
            int c = tid >> 2, kq = (tid & 3) * 16;
            bf16x8 h0, h1, l0, l1;
            #pragma unroll
            for (int u = 0; u < 8; ++u) {
                ushort h, l;
                split2(T[kq + u][c], h, l);     h0[u] = (short)h; l0[u] = (short)l;
                split2(T[kq + 8 + u][c], h, l); h1[u] = (short)h; l1[u] = (short)l;
            }
            ushort* dh = dst + (ll)(c0 + c) * 320 + r0 + kq;
            *(bf16x8*)dh = h0; *(bf16x8*)(dh + 8) = h1;
            *(bf16x8*)(dh + 3 * SZ) = l0; *(bf16x8*)(dh + 3 * SZ + 8) = l1;
        }
    } else if (bid < 375) {                // plain split P
        ll off = (ll)(bid - 225) * 2048 + tid * 8;
        float4 v0 = *(const float4*)(P + off);
        float4 v1 = *(const float4*)(P + off + 4);
        float vals[8] = {v0.x,v0.y,v0.z,v0.w,v1.x,v1.y,v1.z,v1.w};
        bf16x8 hv, lv;
        #pragma unroll
        for (int u = 0; u < 8; ++u) { ushort h,l; split2(vals[u],h,l);
                                      hv[u]=(short)h; lv[u]=(short)l; }
        *(bf16x8*)(Ps + off) = hv;
        *(bf16x8*)(Ps + off + 3 * SZ) = lv;
    } else if (bid < 383) {                // plain split emb
        ll off = (ll)(bid - 375) * 2048 + tid * 8;
        float4 v0 = *(const float4*)(emb + off);
        float4 v1 = *(const float4*)(emb + off + 4);
        float vals[8] = {v0.x,v0.y,v0.z,v0.w,v1.x,v1.y,v1.z,v1.w};
        bf16x8 hv, lv;
        #pragma unroll
        for (int u = 0; u < 8; ++u) { ushort h,l; split2(vals[u],h,l);
                                      hv[u]=(short)h; lv[u]=(short)l; }
        *(bf16x8*)(embs + off) = hv;
        *(bf16x8*)(embs + off + 16384) = lv;
    } else if (bid < 387) {                // transpose-split emb
        int t = bid - 383;
        int r0 = (t >> 1) * 64, c0 = (t & 1) * 64;
        {
            int r = tid >> 2, cq = (tid & 3) * 4;
            *(float4*)&T[r][cq]      = *(const float4*)(emb + (ll)(r0 + r) * 128 + c0 + cq);
            *(float4*)&T[r][cq + 16] = *(const float4*)(emb + (ll)(r0 + r) * 128 + c0 + cq + 16);
            *(float4*)&T[r][cq + 32] = *(const float4*)(emb + (ll)(r0 + r) * 128 + c0 + cq + 32);
            *(float4*)&T[r][cq + 48] = *(const float4*)(emb + (ll)(r0 + r) * 128 + c0 + cq + 48);
        }
        __syncthreads();
        {
            int c = tid >> 2, kq = (tid & 3) * 16;
            bf16x8 h0, h1, l0, l1;
            #pragma unroll
            for (int u = 0; u < 8; ++u) {
                ushort h, l;
                split2(T[kq + u][c], h, l);     h0[u]=(short)h; l0[u]=(short)l;
                split2(T[kq + 8 + u][c], h, l); h1[u]=(short)h; l1[u]=(short)l;
            }
            ushort* dh = embTs + (ll)(c0 + c) * 128 + r0 + kq;
            *(bf16x8*)dh = h0; *(bf16x8*)(dh + 8) = h1;
            *(bf16x8*)(dh + 16384) = l0; *(bf16x8*)(dh + 16384 + 8) = l1;
        }
    } else {                               // q0[c][i]
        ll base = (ll)(bid - 387) * 2048;
        #pragma unroll
        for (int s = 0; s < 8; ++s) {
            ll id = base + s * 256 + tid;
            int c = (int)(id / 320), i = (int)(id % 320);
            q0[id] = (i >= 192) ? emb[(ll)(i - 192) * 128 + c] : 0.f;
        }
    }
}

// Sum 4 partials; write GxS splits (both triangles) + T1s band splits. Grid 240.
__global__ __launch_bounds__(256) void gram_red_k(const float* __restrict__ part,
                                                  ushort* __restrict__ GxS,
                                                  ushort* __restrict__ T1s)
{
    int bt = blockIdx.x;
    int b = bt / 15, t = bt % 15;
    int ti = 0, rem = t;
    while (rem >= 5 - ti) { rem -= 5 - ti; ++ti; }
    int tj = ti + rem;
    int i0 = ti * 64, j0 = tj * 64;
    int tid = threadIdx.x;
    int tx = tid & 15, rg = tid >> 4;
    bool wi = (ti == 0 || ti >= 3);
    bool wj = (tj == 0 || tj >= 3);
    ushort* Gb = GxS + (ll)b * SZ;
    ushort* Tsb = T1s + (ll)b * SZ;
    #pragma unroll
    for (int m = 0; m < 4; ++m) {
        int r = rg * 4 + m;
        float s[4] = {};
        for (int p = 0; p < 4; ++p) {
            const float* src = part + (((ll)p * 16 + b) * 15 + t) * 4096 + r * 64 + tx * 4;
            float4 v = *(const float4*)src;
            s[0]+=v.x; s[1]+=v.y; s[2]+=v.z; s[3]+=v.w;
        }
        #pragma unroll
        for (int u = 0; u < 4; ++u) {
            ushort h, l; split2(s[u], h, l);
            ll rd = (ll)(i0 + r) * 320 + j0 + tx * 4 + u;
            ll rt = (ll)(j0 + tx * 4 + u) * 320 + (i0 + r);
            Gb[rd] = h; Gb[rd + 16 * SZ] = l;
            Gb[rt] = h; Gb[rt + 16 * SZ] = l;
            if (wi) { Tsb[rd] = h; Tsb[rd + 16 * SZ] = l; }
            if (wj) { Tsb[rt] = h; Tsb[rt + 16 * SZ] = l; }
        }
    }
}

// ---------------------------------------------------------------------------
// Packed MFMA bf16x3 job kernel (round-8-verified): XCD swizzle + LDS B + prefetch.
// ---------------------------------------------------------------------------
struct CJob {
    const ushort *Ah, *Bh;
    const void *Ci, *Ci2;
    float* C; ushort* Cs;
    ll aB, bB, ciB, ci2B, cB, csB;
    ll aLo, bLo, csLo, ciLo, ci2Lo;
    int aS, bS, ciS, ci2S, cS, csS;
    int K, tN, tpb, flags;
    int swzQ, swzR;
    float alpha;
};
struct CPack { CJob j[4]; };

__global__ __launch_bounds__(256) void mchain_k(CPack jp, int c0, int c1, int c2)
{
    int bid = blockIdx.x;
    int ji, local;
    if (bid < c0)      { ji = 0; local = bid; }
    else if (bid < c1) { ji = 1; local = bid - c0; }
    else if (bid < c2) { ji = 2; local = bid - c1; }
    else               { ji = 3; local = bid - c2; }
    CJob j = jp.j[ji];
    int xcd = local & 7, sidx = local >> 3;
    int base = (xcd < j.swzR) ? xcd * (j.swzQ + 1)
                              : j.swzR * (j.swzQ + 1) + (xcd - j.swzR) * j.swzQ;
    int swz = base + sidx;
    int bz = swz / j.tpb;
    int t = swz - bz * j.tpb;
    int i0 = (t / j.tN) * 64, j0 = (t % j.tN) * 64;
    int tid = threadIdx.x;
    int wv = tid >> 6, lane = tid & 63;
    int lr = lane & 15, kb = (lane >> 4) * 8;
    f32x4 hh[4], cx[4];
    f32x4 zz = {0.f,0.f,0.f,0.f};
    #pragma unroll
    for (int f = 0; f < 4; ++f) { hh[f] = zz; cx[f] = zz; }

    __shared__ __align__(16) ushort Bsh[2][2][2560];

    if (j.K > 0) {
        int srow = tid >> 2, skq = (tid & 3) * 8;
        const ushort* Bg = j.Bh + (ll)bz * j.bB + (ll)(j0 + srow) * j.bS + skq;
        const ushort* Ar = j.Ah + (ll)bz * j.aB + (ll)(i0 + wv * 16 + lr) * j.aS + kb;
        bf16x8 svh, svl, ah, al, ahn, aln;
        svh = *(const bf16x8*)Bg;
        svl = *(const bf16x8*)(Bg + j.bLo);
        *(bf16x8*)&Bsh[0][0][srow * 40 + skq] = svh;
        *(bf16x8*)&Bsh[0][1][srow * 40 + skq] = svl;
        ah = *(const bf16x8*)Ar;
        al = *(const bf16x8*)(Ar + j.aLo);
        __syncthreads();
        int nit = j.K >> 5;
        for (int it = 0; it < nit; ++it) {
            int cur = it & 1;
            bool more = (it + 1 < nit);
            if (more) {
                int k1 = (it + 1) << 5;
                svh = *(const bf16x8*)(Bg + k1);
                svl = *(const bf16x8*)(Bg + j.bLo + k1);
                ahn = *(const bf16x8*)(Ar + k1);
                aln = *(const bf16x8*)(Ar + j.aLo + k1);
            }
            #pragma unroll
            for (int f = 0; f < 4; ++f) {
                bf16x8 bh = *(const bf16x8*)&Bsh[cur][0][(f * 16 + lr) * 40 + kb];
                bf16x8 bl = *(const bf16x8*)&Bsh[cur][1][(f * 16 + lr) * 40 + kb];
                hh[f] = __builtin_amdgcn_mfma_f32_16x16x32_bf16(ah, bh, hh[f], 0, 0, 0);
                cx[f] = __builtin_amdgcn_mfma_f32_16x16x32_bf16(ah, bl, cx[f], 0, 0, 0);
                cx[f] = __builtin_amdgcn_mfma_f32_16x16x32_bf16(al, bh, cx[f], 0, 0, 0);
            }
            if (more) {
                *(bf16x8*)&Bsh[cur ^ 1][0][srow * 40 + skq] = svh;
                *(bf16x8*)&Bsh[cur ^ 1][1][srow * 40 + skq] = svl;
                ah = ahn; al = aln;
            }
            __syncthreads();
        }
    }
    const float* Cif = (const float*)j.Ci;
    const ushort* Ciu = (const ushort*)j.Ci;
    const float* Ci2f = (const float*)j.Ci2;
    const ushort* Ci2u = (const ushort*)j.Ci2;
    float* Cp = j.C + (ll)bz * j.cB;
    ushort* Csp = j.Cs + (ll)bz * j.csB;
    int r0 = i0 + wv * 16 + ((lane >> 4) << 2);
    #pragma unroll
    for (int f = 0; f < 4; ++f) {
        int col = j0 + f * 16 + lr;
        #pragma unroll
        for (int r = 0; r < 4; ++r) {
            int row = r0 + r;
            float v = j.alpha * (hh[f][r] + cx[f][r]);
            if (j.flags & 1)
                v += Cif[(ll)bz * j.ciB + (ll)row * j.ciS + col];
            if (j.flags & 32) {
                const ushort* p = Ciu + (ll)bz * j.ciB + (ll)row * j.ciS + col;
                v += us2f(p[0], p[j.ciLo]);
            }
            if (j.flags & 64) {
                const ushort* b2 = Ci2u + (ll)bz * j.ci2B;
                if (j.flags & 2) { const ushort* p = b2 + (ll)row * j.ci2S + col;
                                   v += us2f(p[0], p[j.ci2Lo]); }
                if (j.flags & 4) { const ushort* p = b2 + (ll)col * j.ci2S + row;
                                   v += us2f(p[0], p[j.ci2Lo]); }
            } else {
                if (j.flags & 2) v += Ci2f[(ll)bz * j.ci2B + (ll)row * j.ci2S + col];
                if (j.flags & 4) v += Ci2f[(ll)bz * j.ci2B + (ll)col * j.ci2S + row];
            }
            if (j.flags & 8) Cp[(ll)row * j.cS + col] = v;
            if (j.flags & 16) {
                ushort h, l; split2(v, h, l);
                ushort* p = Csp + (ll)row * j.csS + col;
                p[0] = h; p[j.csLo] = l;
            }
        }
    }
}

// ---------------------------------------------------------------------------
// MFMA logits + softmax v2: 1024 blocks (32 n-rows x 128 cats each), XCD
// swizzle, 4 waves = 2 rowgroups x 2 col-halves, stride-33 LDS (conflict-free),
// cross-wave softmax via LDS partials.
// ---------------------------------------------------------------------------
__global__ __launch_bounds__(256) void logits_mfma_k(const float* __restrict__ x,
                                                     const ushort* __restrict__ LBs,
                                                     float* __restrict__ logits,
                                                     float* __restrict__ pred)
{
    int flat = blockIdx.x;                 // 0..1023
    int swzb = (flat & 7) * 128 + (flat >> 3);
    int b = swzb >> 6;
    int i0 = (swzb & 63) * 32;
    const float* X = x + (ll)b * 320 * 2048;
    const ushort* LB = LBs + (ll)b * RS;
    __shared__ float Xs_[2][32][33];
    __shared__ float pmL[2][32], psL[2][32];
    int tid = threadIdx.x;
    int wv = tid >> 6, lane = tid & 63;
    int lr = lane & 15, g = lane >> 4, kb = g * 8;
    int rowg = (wv & 1) * 16, ch = wv >> 1, colh = ch * 64;
    int lkk = tid >> 3, lq = (tid & 7) * 4;
    f32x4 hh[4], cx[4];
    f32x4 zz = {0.f,0.f,0.f,0.f};
    #pragma unroll
    for (int f = 0; f < 4; ++f) { hh[f] = zz; cx[f] = zz; }
    float4 pa;
    auto glb = [&](int k0) {
        pa = *(const float4*)(X + (ll)(k0 + lkk) * 2048 + i0 + lq);
    };
    auto stl = [&](int buf) {
        float* p = &Xs_[buf][lkk][lq];
        p[0] = pa.x; p[1] = pa.y; p[2] = pa.z; p[3] = pa.w;
    };
    glb(0); stl(0);
    __syncthreads();
    for (int it = 0; it < 10; ++it) {
        int cur = it & 1;
        if (it < 9) glb((it + 1) * 32);
        bf16x8 ah, al;
        #pragma unroll
        for (int u = 0; u < 8; ++u) {
            ushort h, l;
            split2(Xs_[cur][kb + u][rowg + lr], h, l);
            ah[u] = (short)h; al[u] = (short)l;
        }
        #pragma unroll
        for (int f = 0; f < 4; ++f) {
            const ushort* Bp = LB + (ll)(colh + f * 16 + lr) * 320 + it * 32 + kb;
            bf16x8 bh = *(const bf16x8*)Bp;
            bf16x8 bl = *(const bf16x8*)(Bp + 16 * RS);
            hh[f] = __builtin_amdgcn_mfma_f32_16x16x32_bf16(ah, bh, hh[f], 0, 0, 0);
            cx[f] = __builtin_amdgcn_mfma_f32_16x16x32_bf16(ah, bl, cx[f], 0, 0, 0);
            cx[f] = __builtin_amdgcn_mfma_f32_16x16x32_bf16(al, bh, cx[f], 0, 0, 0);
        }
        if (it < 9) stl(cur ^ 1);
        __syncthreads();
    }
    float v[4][4];
    #pragma unroll
    for (int r = 0; r < 4; ++r)
        #pragma unroll
        for (int f = 0; f < 4; ++f) v[r][f] = hh[f][r] + cx[f][r];
    // phase 1: per-wave col-max partials (shfl within 16-lane group)
    #pragma unroll
    for (int r = 0; r < 4; ++r) {
        float m = fmaxf(fmaxf(v[r][0], v[r][1]), fmaxf(v[r][2], v[r][3]));
        #pragma unroll
        for (int off = 8; off; off >>= 1) m = fmaxf(m, __shfl_xor(m, off));
        if (lr == 0) pmL[ch][rowg + g * 4 + r] = m;
    }
    __syncthreads();
    // phase 2: exp + partial sums
    float ev[4][4];
    #pragma unroll
    for (int r = 0; r < 4; ++r) {
        int blr = rowg + g * 4 + r;
        float mx = fmaxf(pmL[0][blr], pmL[1][blr]);
        float s = 0.f;
        #pragma unroll
        for (int f = 0; f < 4; ++f) { ev[r][f] = expf(v[r][f] - mx); s += ev[r][f]; }
        #pragma unroll
        for (int off = 8; off; off >>= 1) s += __shfl_xor(s, off);
        if (lr == 0) psL[ch][blr] = s;
    }
    __syncthreads();
    // phase 3: write
    #pragma unroll
    for (int r = 0; r < 4; ++r) {
        int blr = rowg + g * 4 + r;
        float inv = 1.f / (psL[0][blr] + psL[1][blr]);
        ll ro = ((ll)b * 2048 + i0 + blr) * 128 + colh + lr;
        #pragma unroll
        for (int f = 0; f < 4; ++f) {
            logits[ro + f * 16] = v[r][f];
            pred[ro + f * 16] = ev[r][f] * inv;
        }
    }
}

extern "C" void kernel_launch(void* const* d_in, const int* in_sizes, int n_in,
                              void* d_out, int out_size, void* d_ws, size_t ws_size,
                              hipStream_t stream)
{
    const float* x   = (const float*)d_in[0];
    const float* emb = (const float*)d_in[1];
    const float* Wq  = (const float*)d_in[2];
    const float* Wk  = (const float*)d_in[3];
    const float* Wv  = (const float*)d_in[4];
    const float* P   = (const float*)d_in[5];

    float* logits = (float*)d_out;
    float* pred   = logits + (ll)16 * 2048 * 128;

    float* w = (float*)d_ws;
    auto takef = [&](ll n) { float* p = w; w += n; return p; };
    ushort* GxS  = (ushort*)takef(16 * SZ); // alias: Xs (after LA)
    ushort* T1s  = (ushort*)takef(16 * SZ); // alias: Zts (after LG)
    ushort* Gs   = (ushort*)takef(16 * SZ);
    ushort* As   = (ushort*)takef(16 * SZ);
    ushort* Us   = (ushort*)takef(16 * SZ);
    float*  ATsF = takef(48 * SZ);          // part aliases front (3.93M < 4.92M)
    ushort* ATs  = (ushort*)ATsF;
    ushort* PVs  = (ushort*)takef(3 * SZ);
    ushort* KQTs = (ushort*)takef(3 * SZ);
    ushort* KQs  = (ushort*)takef(3 * SZ);
    ushort* Ps   = (ushort*)takef(3 * SZ);
    ushort* WqTs = (ushort*)takef(3 * SZ);
    ushort* WkTs = (ushort*)takef(3 * SZ);
    ushort* WvTs = (ushort*)takef(3 * SZ);
    ushort* embs = (ushort*)takef(16384);
    ushort* embTs= (ushort*)takef(16384);
    float*  q0f  = takef(RS);
    ushort* q1s  = (ushort*)takef(16 * RS); // alias: q3s
    ushort* q2s  = (ushort*)takef(16 * RS);
    ushort* LBs  = (ushort*)takef(16 * RS);
    ushort* Xs   = GxS;
    ushort* Zts  = T1s;
    float*  part = ATsF;
    ushort* q3s  = q1s;
    const float cinv = 1.f / 2047.f;

    auto JB = [](const ushort* Ah, ll aB, int aS, ll aLo,
                 const ushort* Bh, ll bB, int bS, ll bLo,
                 int K, int tM, int tN, float alpha, int flags,
                 const void* Ci, ll ciB, int ciS, ll ciLo,
                 const void* Ci2, ll ci2B, int ci2S, ll ci2Lo,
                 float* C, ll cB, int cS,
                 ushort* Cs, ll csB, int csS, ll csLo) {
        CJob j;
        j.Ah = Ah; j.Bh = Bh;
        j.Ci = Ci; j.Ci2 = Ci2; j.C = C; j.Cs = Cs;
        j.aB = aB; j.bB = bB; j.ciB = ciB; j.ci2B = ci2B; j.cB = cB; j.csB = csB;
        j.aLo = aLo; j.bLo = bLo; j.csLo = csLo; j.ciLo = ciLo; j.ci2Lo = ci2Lo;
        j.aS = aS; j.bS = bS; j.ciS = ciS; j.ci2S = ci2S; j.cS = cS; j.csS = csS;
        j.K = K; j.tN = tN; j.tpb = tM * tN; j.flags = flags; j.alpha = alpha;
        j.swzQ = 0; j.swzR = 0;
        return j;
    };
    auto fire = [&](const CJob* js, const int* nb, int n) {
        CPack jp;
        int cum[4], tot = 0;
        for (int i = 0; i < 4; ++i) {
            jp.j[i] = js[i < n ? i : 0];
            if (i < n) { jp.j[i].swzQ = nb[i] >> 3; jp.j[i].swzR = nb[i] & 7; }
            tot += (i < n ? nb[i] : 0);
            cum[i] = tot;
        }
        mchain_k<<<tot, 256, 0, stream>>>(jp, cum[0], cum[1], cum[2]);
    };

    // 1) fused gram + setup splits
    gram_sp_k<<<1367, 256, 0, stream>>>(x, part, Wq, Wk, Wv, P, emb,
                                        WqTs, WkTs, WvTs, Ps, embs, embTs, q0f);
    gram_red_k<<<240, 256, 0, stream>>>(part, GxS, T1s);
    // 4) LA: T1mid = E*Gx[64:192] | PV = P*Wv | KQT = Wq^T Wk | KQ = Wk^T Wq
    {
        CJob js[4] = {
            JB(embs, 0, 128, 16384,  GxS + 64, SZ, 320, 16*SZ,  128, 2, 5, 1.f, 16,
               0,0,0,0, 0,0,0,0,  0,0,0,  T1s + 64*320, SZ, 320, 16*SZ),
            JB(Ps, SZ, 320, 3*SZ,  WvTs, SZ, 320, 3*SZ,  320, 5, 5, 1.f, 16,
               0,0,0,0, 0,0,0,0,  0,0,0,  PVs, SZ, 320, 3*SZ),
            JB(WqTs, SZ, 320, 3*SZ,  WkTs, SZ, 320, 3*SZ,  320, 5, 5, 1.f, 16,
               0,0,0,0, 0,0,0,0,  0,0,0,  KQTs, SZ, 320, 3*SZ),
            JB(WkTs, SZ, 320, 3*SZ,  WqTs, SZ, 320, 3*SZ,  320, 5, 5, 1.f, 16,
               0,0,0,0, 0,0,0,0,  0,0,0,  KQs, SZ, 320, 3*SZ)};
        int nb[4] = {160, 75, 75, 75};
        fire(js, nb, 4);
    }
    // 5) LG: Gmid = T1[:,64:192]*E^T | G band col copies (Ci = T1s splits)
    {
        CJob js[3] = {
            JB(T1s + 64, SZ, 320, 16*SZ,  embs, 0, 128, 16384,  128, 5, 2, 1.f, 16,
               0,0,0,0, 0,0,0,0,  0,0,0,  Gs + 64, SZ, 320, 16*SZ),
            JB(0,0,0,0, 0,0,0,0,  0, 5, 1, 0.f, 32|16,
               T1s, SZ, 320, 16*SZ, 0,0,0,0,  0,0,0,  Gs, SZ, 320, 16*SZ),
            JB(0,0,0,0, 0,0,0,0,  0, 5, 2, 0.f, 32|16,
               T1s + 192, SZ, 320, 16*SZ, 0,0,0,0,  0,0,0,  Gs + 192, SZ, 320, 16*SZ)};
        int nb[3] = {160, 80, 160};
        fire(js, nb, 3);
    }
    // 6..13) layers
    for (int l = 0; l < 3; ++l) {
        const ushort* PVl = PVs + (ll)l * SZ;
        const ushort* KQTl = KQTs + (ll)l * SZ;
        const ushort* KQl = KQs + (ll)l * SZ;
        ushort* ATl = ATs + (ll)l * 16 * SZ;
        if (l < 2) {
            CJob s1[2] = {
                JB(PVl, 0, 320, 3*SZ,  Gs, SZ, 320, 16*SZ,  320, 5, 5, 1.f, 16,
                   0,0,0,0, 0,0,0,0,  0,0,0,  Xs, SZ, 320, 16*SZ),
                JB(Gs, SZ, 320, 16*SZ,  KQl, 0, 320, 3*SZ,  320, 5, 5, 1.f, 16,
                   0,0,0,0, 0,0,0,0,  0,0,0,  Zts, SZ, 320, 16*SZ)};
            int n1[2] = {400, 400};
            fire(s1, n1, 2);
            CJob s2[3] = {
                JB(Xs, SZ, 320, 16*SZ,  KQTl, 0, 320, 3*SZ,  320, 5, 5, cinv, 16,
                   0,0,0,0, 0,0,0,0,  0,0,0,  As, SZ, 320, 16*SZ),
                JB(KQTl, 0, 320, 3*SZ,  Xs, SZ, 320, 16*SZ,  320, 5, 5, cinv, 16,
                   0,0,0,0, 0,0,0,0,  0,0,0,  ATl, SZ, 320, 48*SZ),
                JB(Xs, SZ, 320, 16*SZ,  Zts, SZ, 320, 16*SZ,  320, 5, 5, cinv, 16,
                   0,0,0,0, 0,0,0,0,  0,0,0,  Us, SZ, 320, 16*SZ)};
            int n2[3] = {400, 400, 400};
            fire(s2, n2, 3);
            CJob s3[1] = {
                JB(Us, SZ, 320, 16*SZ,  As, SZ, 320, 16*SZ,  320, 5, 5, 1.f, 16|32|2|4|64,
                   Gs, SZ, 320, 16*SZ,  Us, SZ, 320, 16*SZ,  0,0,0,  Gs, SZ, 320, 16*SZ)};
            int n3[1] = {400};
            fire(s3, n3, 1);
        } else {
            CJob s1[1] = {
                JB(PVl, 0, 320, 3*SZ,  Gs, SZ, 320, 16*SZ,  320, 5, 5, 1.f, 16,
                   0,0,0,0, 0,0,0,0,  0,0,0,  Xs, SZ, 320, 16*SZ)};
            int n1[1] = {400};
            fire(s1, n1, 1);
            CJob s2[1] = {
                JB(KQTl, 0, 320, 3*SZ,  Xs, SZ, 320, 16*SZ,  320, 5, 5, cinv, 16,
                   0,0,0,0, 0,0,0,0,  0,0,0,  ATl, SZ, 320, 48*SZ)};
            int n2[1] = {400};
            fire(s2, n2, 1);
        }
    }
    // 14) q1 = q0 + E^T * A2[192:,:]
    {
        CJob js[1] = {
            JB(embTs, 0, 128, 16384,  ATs + 2*16*SZ + 192, SZ, 320, 48*SZ,  128, 2, 5, 1.f, 1|16,
               q0f, 0, 320, 0, 0,0,0,0,  0,0,0,  q1s, RS, 320, 16*RS)};
        int nb[1] = {160};
        fire(js, nb, 1);
    }
    // 15) q2 = q1 + q1*A1
    {
        CJob js[1] = {
            JB(q1s, RS, 320, 16*RS,  ATs + 1*16*SZ, SZ, 320, 48*SZ,  320, 2, 5, 1.f, 32|16,
               q1s, RS, 320, 16*RS, 0,0,0,0,  0,0,0,  q2s, RS, 320, 16*RS)};
        int nb[1] = {160};
        fire(js, nb, 1);
    }
    // 16) q3 = q2 + q2*A0
    {
        CJob js[1] = {
            JB(q2s, RS, 320, 16*RS,  ATs, SZ, 320, 48*SZ,  320, 2, 5, 1.f, 32|16,
               q2s, RS, 320, 16*RS, 0,0,0,0,  0,0,0,  q3s, RS, 320, 16*RS)};
        int nb[1] = {160};
        fire(js, nb, 1);
    }
    // 17) LB = q3*W : mid mfma + band copies
    {
        CJob js[3] = {
            JB(q3s + 64, RS, 320, 16*RS,  embTs, 0, 128, 16384,  128, 2, 2, 1.f, 16,
               0,0,0,0, 0,0,0,0,  0,0,0,  LBs + 64, RS, 320, 16*RS),
            JB(0,0,0,0, 0,0,0,0,  0, 2, 1, 0.f, 32|16,
               q3s, RS, 320, 16*RS, 0,0,0,0,  0,0,0,  LBs, RS, 320, 16*RS),
            JB(0,0,0,0, 0,0,0,0,  0, 2, 2, 0.f, 32|16,
               q3s + 192, RS, 320, 16*RS, 0,0,0,0,  0,0,0,  LBs + 192, RS, 320, 16*RS)};
        int nb[3] = {64, 32, 64};
        fire(js, nb, 3);
    }
    // 18) logits + softmax (MFMA, 1024 blocks)
    logits_mfma_k<<<1024, 256, 0, stream>>>(x, LBs, logits, pred);
}